// Round 4
// baseline (1994.321 us; speedup 1.0000x reference)
//
#include <hip/hip_runtime.h>
#include <hip/hip_bf16.h>
#include <math.h>

// Problem constants (from reference)
#define NB   2
#define NT   4096
#define ND   1024
#define NDFF 2048
#define NE   8
#define NK   2
#define NN   (NB * NT)   // 8192 tokens
#define NCAP 2560        // ceil(1.25 * NN * NK / NE)

__device__ __forceinline__ float gelu_exact(float v) {
  // jax.nn.gelu(approximate=False): 0.5*x*(1+erf(x/sqrt(2)))
  return 0.5f * v * (1.0f + erff(v * 0.70710678118654752f));
}

// ---------------------------------------------------------------------------
// Router: one wave per token. logits = x @ gw^T (E=8), softmax, top-2,
// dispatch weights. Accumulates p_sum (softmax prob sums) and f_cnt
// (top-2 assignment counts) for the aux loss.
// ---------------------------------------------------------------------------
__global__ __launch_bounds__(256) void router_kernel(
    const float* __restrict__ x, const float* __restrict__ gw,
    int* __restrict__ top_i, float* __restrict__ disp_w,
    float* __restrict__ p_sum, int* __restrict__ f_cnt) {
  __shared__ float s_p[NE];
  __shared__ int s_f[NE];
  if (threadIdx.x < NE) { s_p[threadIdx.x] = 0.0f; s_f[threadIdx.x] = 0; }
  __syncthreads();

  const int lane = threadIdx.x & 63;
  const int wv = threadIdx.x >> 6;
  const int n = blockIdx.x * 4 + wv;

  const float4* xr = (const float4*)(x + (size_t)n * ND);
  float acc[NE];
#pragma unroll
  for (int e = 0; e < NE; ++e) acc[e] = 0.0f;

#pragma unroll
  for (int q = 0; q < 4; ++q) {
    float4 xv = xr[lane * 4 + q];
#pragma unroll
    for (int e = 0; e < NE; ++e) {
      float4 g = ((const float4*)(gw + (size_t)e * ND))[lane * 4 + q];
      acc[e] += xv.x * g.x + xv.y * g.y + xv.z * g.z + xv.w * g.w;
    }
  }
  // full-wave butterfly reduction (all lanes end with the totals)
#pragma unroll
  for (int m = 1; m < 64; m <<= 1) {
#pragma unroll
    for (int e = 0; e < NE; ++e) acc[e] += __shfl_xor(acc[e], m, 64);
  }

  float mx = acc[0];
#pragma unroll
  for (int e = 1; e < NE; ++e) mx = fmaxf(mx, acc[e]);
  float p[NE];
  float s = 0.0f;
#pragma unroll
  for (int e = 0; e < NE; ++e) { p[e] = expf(acc[e] - mx); s += p[e]; }
  float inv = 1.0f / s;
#pragma unroll
  for (int e = 0; e < NE; ++e) p[e] *= inv;

  // top-2 (strict > keeps lowest index on ties, matching lax.top_k)
  int i1 = 0; float v1 = p[0];
#pragma unroll
  for (int e = 1; e < NE; ++e) { if (p[e] > v1) { v1 = p[e]; i1 = e; } }
  int i2 = 0; float v2 = -1.0f;
#pragma unroll
  for (int e = 0; e < NE; ++e) { if (e != i1 && p[e] > v2) { v2 = p[e]; i2 = e; } }

  if (lane == 0) {
    float dsum = v1 + v2 + 1e-9f;
    top_i[n * NK + 0] = i1;
    top_i[n * NK + 1] = i2;
    disp_w[n * NK + 0] = v1 / dsum;
    disp_w[n * NK + 1] = v2 / dsum;
#pragma unroll
    for (int e = 0; e < NE; ++e) atomicAdd(&s_p[e], p[e]);
    atomicAdd(&s_f[i1], 1);
    atomicAdd(&s_f[i2], 1);
  }
  __syncthreads();
  if (threadIdx.x < NE) {
    atomicAdd(&p_sum[threadIdx.x], s_p[threadIdx.x]);
    atomicAdd(&f_cnt[threadIdx.x], s_f[threadIdx.x]);
  }
}

// ---------------------------------------------------------------------------
// Capacity scan: single block, 8 waves, wave e scans the slot-major
// assignment stream (slot 0 tokens 0..N-1, then slot 1) with ballot-based
// prefix counts -> exact token-order arrival positions per expert.
// Scatters kept (token, weight) into per-expert lists. Also emits aux loss.
// ---------------------------------------------------------------------------
__global__ __launch_bounds__(512) void scan_kernel(
    const int* __restrict__ top_i, const float* __restrict__ disp_w,
    int* __restrict__ routed_tok, float* __restrict__ routed_w,
    int* __restrict__ counts, const float* __restrict__ p_sum,
    const int* __restrict__ f_cnt, float* __restrict__ aux_out) {
  __shared__ __align__(16) int s_top[NN * NK];
  for (int i = threadIdx.x; i < (NN * NK) / 4; i += 512)
    ((int4*)s_top)[i] = ((const int4*)top_i)[i];
  __syncthreads();

  const int e = threadIdx.x >> 6;    // wave id = expert
  const int lane = threadIdx.x & 63;
  int cnt = 0;
  for (int c = 0; c < (NN * NK) / 64; ++c) {
    int a = c * 64 + lane;       // slot-major flat index
    int n = a & (NN - 1);        // token
    int k = a >> 13;             // slot (NN = 2^13)
    bool m = (s_top[n * NK + k] == e);
    unsigned long long mask = __ballot(m);
    if (m) {
      int pos = cnt + __popcll(mask & ((1ull << lane) - 1ull));
      if (pos < NCAP) {
        routed_tok[e * NCAP + pos] = n;
        routed_w[e * NCAP + pos] = disp_w[n * NK + k];
      }
    }
    cnt += (int)__popcll(mask);
  }
  if (lane == 0) counts[e] = (cnt < NCAP) ? cnt : NCAP;

  if (threadIdx.x == 0) {
    float aux = 0.0f;
    for (int j = 0; j < NE; ++j)
      aux += (p_sum[j] / (float)NN) * ((float)f_cnt[j] / (float)NN);
    aux_out[0] = aux * (float)NE;
  }
}

// ---------------------------------------------------------------------------
// GEMM1: H[r, :] = gelu(x[tok_r, :] @ W1[e] + b1[e])   (gathered A rows)
// 128x128 tile, BK=16, 256 threads, 8x8 per thread (split +-64 fragments
// to keep LDS reads <=2-way bank aliased).
// ---------------------------------------------------------------------------
__global__ __launch_bounds__(256) void gemm1_kernel(
    const float* __restrict__ x, const float* __restrict__ W1,
    const float* __restrict__ b1, const int* __restrict__ routed_tok,
    const int* __restrict__ counts, float* __restrict__ H,
    int e0, size_t h_stride) {
  const int e = e0 + blockIdx.z;
  const int count = counts[e];
  const int row0 = blockIdx.y * 128;
  if (row0 >= count) return;
  const int col0 = blockIdx.x * 128;
  const float* W = W1 + (size_t)e * ND * NDFF;
  float* Hb = H + (size_t)blockIdx.z * h_stride;

  __shared__ __align__(16) float As[16][128];
  __shared__ __align__(16) float Bs[16][128];

  const int tid = threadIdx.x;
  const int arow = tid >> 1;        // 0..127
  const int aq = (tid & 1) * 8;     // 0 or 8 (float offset in K-tile)
  const int r = row0 + arow;
  const int tok = routed_tok[e * NCAP + (r < count ? r : 0)];
  const float* Arow = x + (size_t)tok * ND;
  const int bk = tid >> 5;          // 0..7
  const int bc = (tid & 31) * 4;    // 0..124
  const int ty = tid >> 4, tx = tid & 15;

  float c[8][8] = {};

  for (int k0 = 0; k0 < ND; k0 += 16) {
    float4 av0 = *(const float4*)(Arow + k0 + aq);
    float4 av1 = *(const float4*)(Arow + k0 + aq + 4);
    float4 bv0 = *(const float4*)(W + (size_t)(k0 + bk) * NDFF + col0 + bc);
    float4 bv1 = *(const float4*)(W + (size_t)(k0 + bk + 8) * NDFF + col0 + bc);
    __syncthreads();
    As[aq + 0][arow] = av0.x; As[aq + 1][arow] = av0.y;
    As[aq + 2][arow] = av0.z; As[aq + 3][arow] = av0.w;
    As[aq + 4][arow] = av1.x; As[aq + 5][arow] = av1.y;
    As[aq + 6][arow] = av1.z; As[aq + 7][arow] = av1.w;
    *(float4*)&Bs[bk][bc] = bv0;
    *(float4*)&Bs[bk + 8][bc] = bv1;
    __syncthreads();
#pragma unroll
    for (int kk = 0; kk < 16; ++kk) {
      float4 a0 = *(const float4*)&As[kk][ty * 4];
      float4 a1 = *(const float4*)&As[kk][ty * 4 + 64];
      float4 b0 = *(const float4*)&Bs[kk][tx * 4];
      float4 b1r = *(const float4*)&Bs[kk][tx * 4 + 64];
      float ar[8] = {a0.x, a0.y, a0.z, a0.w, a1.x, a1.y, a1.z, a1.w};
      float br[8] = {b0.x, b0.y, b0.z, b0.w, b1r.x, b1r.y, b1r.z, b1r.w};
#pragma unroll
      for (int i = 0; i < 8; ++i)
#pragma unroll
        for (int j = 0; j < 8; ++j)
          c[i][j] = fmaf(ar[i], br[j], c[i][j]);
    }
  }

  const float* b1e = b1 + (size_t)e * NDFF + col0;
#pragma unroll
  for (int i = 0; i < 8; ++i) {
    int rr = row0 + ty * 4 + (i & 3) + (i >> 2) * 64;
    if (rr < count) {
      float* Hr = Hb + (size_t)rr * NDFF + col0;
      float4 v0, v1;
      v0.x = gelu_exact(c[i][0] + b1e[tx * 4 + 0]);
      v0.y = gelu_exact(c[i][1] + b1e[tx * 4 + 1]);
      v0.z = gelu_exact(c[i][2] + b1e[tx * 4 + 2]);
      v0.w = gelu_exact(c[i][3] + b1e[tx * 4 + 3]);
      v1.x = gelu_exact(c[i][4] + b1e[tx * 4 + 64]);
      v1.y = gelu_exact(c[i][5] + b1e[tx * 4 + 65]);
      v1.z = gelu_exact(c[i][6] + b1e[tx * 4 + 66]);
      v1.w = gelu_exact(c[i][7] + b1e[tx * 4 + 67]);
      *(float4*)(Hr + tx * 4) = v0;
      *(float4*)(Hr + tx * 4 + 64) = v1;
    }
  }
}

// ---------------------------------------------------------------------------
// GEMM2: out[tok_r, :] += w_r * (H[r, :] @ W2[e] + b2[e])
// Same tiling; epilogue is a weighted atomicAdd scatter (deterministic:
// <=2 commutative f32 adds per output element onto a zeroed buffer).
// ---------------------------------------------------------------------------
__global__ __launch_bounds__(256) void gemm2_kernel(
    const float* __restrict__ H, const float* __restrict__ W2,
    const float* __restrict__ b2, const int* __restrict__ routed_tok,
    const float* __restrict__ routed_w, const int* __restrict__ counts,
    float* __restrict__ out, int e0, size_t h_stride) {
  const int e = e0 + blockIdx.z;
  const int count = counts[e];
  const int row0 = blockIdx.y * 128;
  if (row0 >= count) return;
  const int col0 = blockIdx.x * 128;
  const float* W = W2 + (size_t)e * NDFF * ND;
  const float* Hb = H + (size_t)blockIdx.z * h_stride;

  __shared__ __align__(16) float As[16][128];
  __shared__ __align__(16) float Bs[16][128];

  const int tid = threadIdx.x;
  const int arow = tid >> 1;
  const int aq = (tid & 1) * 8;
  const float* Arow = Hb + (size_t)(row0 + arow) * NDFF;
  const int bk = tid >> 5;
  const int bc = (tid & 31) * 4;
  const int ty = tid >> 4, tx = tid & 15;

  float c[8][8] = {};

  for (int k0 = 0; k0 < NDFF; k0 += 16) {
    float4 av0 = *(const float4*)(Arow + k0 + aq);
    float4 av1 = *(const float4*)(Arow + k0 + aq + 4);
    float4 bv0 = *(const float4*)(W + (size_t)(k0 + bk) * ND + col0 + bc);
    float4 bv1 = *(const float4*)(W + (size_t)(k0 + bk + 8) * ND + col0 + bc);
    __syncthreads();
    As[aq + 0][arow] = av0.x; As[aq + 1][arow] = av0.y;
    As[aq + 2][arow] = av0.z; As[aq + 3][arow] = av0.w;
    As[aq + 4][arow] = av1.x; As[aq + 5][arow] = av1.y;
    As[aq + 6][arow] = av1.z; As[aq + 7][arow] = av1.w;
    *(float4*)&Bs[bk][bc] = bv0;
    *(float4*)&Bs[bk + 8][bc] = bv1;
    __syncthreads();
#pragma unroll
    for (int kk = 0; kk < 16; ++kk) {
      float4 a0 = *(const float4*)&As[kk][ty * 4];
      float4 a1 = *(const float4*)&As[kk][ty * 4 + 64];
      float4 b0 = *(const float4*)&Bs[kk][tx * 4];
      float4 b1r = *(const float4*)&Bs[kk][tx * 4 + 64];
      float ar[8] = {a0.x, a0.y, a0.z, a0.w, a1.x, a1.y, a1.z, a1.w};
      float br[8] = {b0.x, b0.y, b0.z, b0.w, b1r.x, b1r.y, b1r.z, b1r.w};
#pragma unroll
      for (int i = 0; i < 8; ++i)
#pragma unroll
        for (int j = 0; j < 8; ++j)
          c[i][j] = fmaf(ar[i], br[j], c[i][j]);
    }
  }

  const float* b2e = b2 + (size_t)e * ND + col0;
#pragma unroll
  for (int i = 0; i < 8; ++i) {
    int rr = row0 + ty * 4 + (i & 3) + (i >> 2) * 64;
    if (rr < count) {
      int tok = routed_tok[e * NCAP + rr];
      float wgt = routed_w[e * NCAP + rr];
      float* orow = out + (size_t)tok * ND + col0;
#pragma unroll
      for (int j = 0; j < 8; ++j) {
        int cc = tx * 4 + (j & 3) + (j >> 2) * 64;
        atomicAdd(orow + cc, wgt * (c[i][j] + b2e[cc]));
      }
    }
  }
}

// ---------------------------------------------------------------------------
extern "C" void kernel_launch(void* const* d_in, const int* in_sizes, int n_in,
                              void* d_out, int out_size, void* d_ws, size_t ws_size,
                              hipStream_t stream) {
  const float* x  = (const float*)d_in[0];
  const float* gw = (const float*)d_in[1];
  const float* W1 = (const float*)d_in[2];
  const float* b1 = (const float*)d_in[3];
  const float* W2 = (const float*)d_in[4];
  const float* b2 = (const float*)d_in[5];
  float* out = (float*)d_out;

  // workspace layout
  char* p = (char*)d_ws;
  int*   top_i = (int*)p;    p += (size_t)NN * NK * 4;
  float* dispw = (float*)p;  p += (size_t)NN * NK * 4;
  int*   rtok  = (int*)p;    p += (size_t)NE * NCAP * 4;
  float* rw    = (float*)p;  p += (size_t)NE * NCAP * 4;
  int*   counts = (int*)p;   p += 256;
  float* psum  = (float*)p;
  int*   fcnt  = (int*)(p + 32);
  p += 256;
  float* H = (float*)p;
  size_t base = (size_t)(p - (char*)d_ws);
  size_t h_full = (size_t)NE * NCAP * NDFF * 4;
  const bool fullH = (ws_size >= base + h_full);

  hipMemsetAsync(out, 0, (size_t)NN * ND * 4, stream);  // aux slot written by scan
  hipMemsetAsync(psum, 0, 64, stream);                  // psum + fcnt

  router_kernel<<<NN / 4, 256, 0, stream>>>(x, gw, top_i, dispw, psum, fcnt);
  scan_kernel<<<1, 512, 0, stream>>>(top_i, dispw, rtok, rw, counts, psum, fcnt,
                                     out + (size_t)NN * ND);

  if (fullH) {
    gemm1_kernel<<<dim3(NDFF / 128, NCAP / 128, NE), 256, 0, stream>>>(
        x, W1, b1, rtok, counts, H, 0, (size_t)NCAP * NDFF);
    gemm2_kernel<<<dim3(ND / 128, NCAP / 128, NE), 256, 0, stream>>>(
        H, W2, b2, rtok, rw, counts, out, 0, (size_t)NCAP * NDFF);
  } else {
    for (int e = 0; e < NE; ++e) {
      gemm1_kernel<<<dim3(NDFF / 128, NCAP / 128, 1), 256, 0, stream>>>(
          x, W1, b1, rtok, counts, H, e, 0);
      gemm2_kernel<<<dim3(ND / 128, NCAP / 128, 1), 256, 0, stream>>>(
          H, W2, b2, rtok, rw, counts, out, e, 0);
    }
  }
}

// Round 5
// 1792.964 us; speedup vs baseline: 1.1123x; 1.1123x over previous
//
#include <hip/hip_runtime.h>
#include <hip/hip_bf16.h>
#include <math.h>

// Problem constants (from reference)
#define NB   2
#define NT   4096
#define ND   1024
#define NDFF 2048
#define NE   8
#define NK   2
#define NN   (NB * NT)   // 8192 tokens
#define NCAP 2560        // ceil(1.25 * NN * NK / NE)

typedef unsigned short ushort_t;
typedef __attribute__((ext_vector_type(8))) short bf16x8;   // 8 bf16 = 4 VGPRs (guide §3)
typedef __attribute__((ext_vector_type(4))) float f32x4;

__device__ __forceinline__ float gelu_exact(float v) {
  return 0.5f * v * (1.0f + erff(v * 0.70710678118654752f));
}

// f32 -> bf16 round-to-nearest-even (inputs finite; no NaN handling needed)
__device__ __forceinline__ unsigned short f2bf(float f) {
  unsigned int u = __float_as_uint(f);
  u += 0x7fffu + ((u >> 16) & 1u);
  return (unsigned short)(u >> 16);
}
__device__ __forceinline__ float bf2f(unsigned short h) {
  return __uint_as_float(((unsigned int)h) << 16);
}

// async global->LDS, 16B per lane (lane i writes lds_base + i*16)
__device__ __forceinline__ void gl_lds16(const void* g, void* l) {
  __builtin_amdgcn_global_load_lds(
      (__attribute__((address_space(1))) void*)g,
      (__attribute__((address_space(3))) void*)l, 16, 0, 0);
}

// ---------------------------------------------------------------------------
// Router: one wave per token (unchanged, proven).
// ---------------------------------------------------------------------------
__global__ __launch_bounds__(256) void router_kernel(
    const float* __restrict__ x, const float* __restrict__ gw,
    int* __restrict__ top_i, float* __restrict__ disp_w,
    float* __restrict__ p_sum, int* __restrict__ f_cnt) {
  __shared__ float s_p[NE];
  __shared__ int s_f[NE];
  if (threadIdx.x < NE) { s_p[threadIdx.x] = 0.0f; s_f[threadIdx.x] = 0; }
  __syncthreads();

  const int lane = threadIdx.x & 63;
  const int wv = threadIdx.x >> 6;
  const int n = blockIdx.x * 4 + wv;

  const float4* xr = (const float4*)(x + (size_t)n * ND);
  float acc[NE];
#pragma unroll
  for (int e = 0; e < NE; ++e) acc[e] = 0.0f;

#pragma unroll
  for (int q = 0; q < 4; ++q) {
    float4 xv = xr[lane * 4 + q];
#pragma unroll
    for (int e = 0; e < NE; ++e) {
      float4 g = ((const float4*)(gw + (size_t)e * ND))[lane * 4 + q];
      acc[e] += xv.x * g.x + xv.y * g.y + xv.z * g.z + xv.w * g.w;
    }
  }
#pragma unroll
  for (int m = 1; m < 64; m <<= 1) {
#pragma unroll
    for (int e = 0; e < NE; ++e) acc[e] += __shfl_xor(acc[e], m, 64);
  }

  float mx = acc[0];
#pragma unroll
  for (int e = 1; e < NE; ++e) mx = fmaxf(mx, acc[e]);
  float p[NE];
  float s = 0.0f;
#pragma unroll
  for (int e = 0; e < NE; ++e) { p[e] = expf(acc[e] - mx); s += p[e]; }
  float inv = 1.0f / s;
#pragma unroll
  for (int e = 0; e < NE; ++e) p[e] *= inv;

  int i1 = 0; float v1 = p[0];
#pragma unroll
  for (int e = 1; e < NE; ++e) { if (p[e] > v1) { v1 = p[e]; i1 = e; } }
  int i2 = 0; float v2 = -1.0f;
#pragma unroll
  for (int e = 0; e < NE; ++e) { if (e != i1 && p[e] > v2) { v2 = p[e]; i2 = e; } }

  if (lane == 0) {
    float dsum = v1 + v2 + 1e-9f;
    top_i[n * NK + 0] = i1;
    top_i[n * NK + 1] = i2;
    disp_w[n * NK + 0] = v1 / dsum;
    disp_w[n * NK + 1] = v2 / dsum;
#pragma unroll
    for (int e = 0; e < NE; ++e) atomicAdd(&s_p[e], p[e]);
    atomicAdd(&s_f[i1], 1);
    atomicAdd(&s_f[i2], 1);
  }
  __syncthreads();
  if (threadIdx.x < NE) {
    atomicAdd(&p_sum[threadIdx.x], s_p[threadIdx.x]);
    atomicAdd(&f_cnt[threadIdx.x], s_f[threadIdx.x]);
  }
}

// ---------------------------------------------------------------------------
// Capacity scan (unchanged, proven).
// ---------------------------------------------------------------------------
__global__ __launch_bounds__(512) void scan_kernel(
    const int* __restrict__ top_i, const float* __restrict__ disp_w,
    int* __restrict__ routed_tok, float* __restrict__ routed_w,
    int* __restrict__ counts, const float* __restrict__ p_sum,
    const int* __restrict__ f_cnt, float* __restrict__ aux_out) {
  __shared__ __align__(16) int s_top[NN * NK];
  for (int i = threadIdx.x; i < (NN * NK) / 4; i += 512)
    ((int4*)s_top)[i] = ((const int4*)top_i)[i];
  __syncthreads();

  const int e = threadIdx.x >> 6;
  const int lane = threadIdx.x & 63;
  int cnt = 0;
  for (int c = 0; c < (NN * NK) / 64; ++c) {
    int a = c * 64 + lane;
    int n = a & (NN - 1);
    int k = a >> 13;
    bool m = (s_top[n * NK + k] == e);
    unsigned long long mask = __ballot(m);
    if (m) {
      int pos = cnt + __popcll(mask & ((1ull << lane) - 1ull));
      if (pos < NCAP) {
        routed_tok[e * NCAP + pos] = n;
        routed_w[e * NCAP + pos] = disp_w[n * NK + k];
      }
    }
    cnt += (int)__popcll(mask);
  }
  if (lane == 0) counts[e] = (cnt < NCAP) ? cnt : NCAP;

  if (threadIdx.x == 0) {
    float aux = 0.0f;
    for (int j = 0; j < NE; ++j)
      aux += (p_sum[j] / (float)NN) * ((float)f_cnt[j] / (float)NN);
    aux_out[0] = aux * (float)NE;
  }
}

// ---------------------------------------------------------------------------
// splitx: x f32 -> xhi/xlo bf16 (hi = rn(x), lo = rn(x - hi))
// ---------------------------------------------------------------------------
__global__ __launch_bounds__(256) void splitx_kernel(
    const float* __restrict__ x, ushort_t* __restrict__ xhi,
    ushort_t* __restrict__ xlo) {
  size_t i = (size_t)blockIdx.x * 256 + threadIdx.x;
  float4 v = ((const float4*)x)[i];
  ushort4 h, l;
  h.x = f2bf(v.x); l.x = f2bf(v.x - bf2f(h.x));
  h.y = f2bf(v.y); l.y = f2bf(v.y - bf2f(h.y));
  h.z = f2bf(v.z); l.z = f2bf(v.z - bf2f(h.z));
  h.w = f2bf(v.w); l.w = f2bf(v.w - bf2f(h.w));
  ((ushort4*)xhi)[i] = h;
  ((ushort4*)xlo)[i] = l;
}

// ---------------------------------------------------------------------------
// tsplit: W [E][K][N] f32 -> T [E][N][K] bf16 hi/lo, via 32x32 LDS transpose
// ---------------------------------------------------------------------------
__global__ __launch_bounds__(256) void tsplit_kernel(
    const float* __restrict__ W, ushort_t* __restrict__ Thi,
    ushort_t* __restrict__ Tlo, int K, int N) {
  __shared__ float tile[32][33];
  const int t = threadIdx.x;
  const int n0 = blockIdx.x * 32, k0 = blockIdx.y * 32;
  const int r = t >> 3, c4 = (t & 7) * 4;
  float4 v = *(const float4*)(W + (size_t)blockIdx.z * K * N +
                              (size_t)(k0 + r) * N + n0 + c4);
  tile[r][c4 + 0] = v.x; tile[r][c4 + 1] = v.y;
  tile[r][c4 + 2] = v.z; tile[r][c4 + 3] = v.w;
  __syncthreads();
  const int n = t >> 3, kc = (t & 7) * 4;
  ushort4 h, l;
  float f;
  f = tile[kc + 0][n]; h.x = f2bf(f); l.x = f2bf(f - bf2f(h.x));
  f = tile[kc + 1][n]; h.y = f2bf(f); l.y = f2bf(f - bf2f(h.y));
  f = tile[kc + 2][n]; h.z = f2bf(f); l.z = f2bf(f - bf2f(h.z));
  f = tile[kc + 3][n]; h.w = f2bf(f); l.w = f2bf(f - bf2f(h.w));
  size_t o = (size_t)blockIdx.z * N * K + (size_t)(n0 + n) * K + k0 + kc;
  *(ushort4*)(Thi + o) = h;
  *(ushort4*)(Tlo + o) = l;
}

// ---------------------------------------------------------------------------
// fgemm: split-bf16 MFMA GEMM, 128x256 tile, 8 waves (64x64 each), BK=32.
//  A [rows][K] gathered (MODE1: x via routed_tok; MODE2: H rows direct)
//  B = WT [E][Ntot][K]   (pre-transposed+split weights)
//  MODE1: out = gelu(A@B + bias) -> Hhi/Hlo bf16
//  MODE2: out[tok] += w * (A@B + bias)  (atomic f32, <=2 commutative adds)
// LDS: hi|lo interleaved [row][128B]; logical k-chunk b (0-3 hi, 4-7 lo) at
// physical b' = b ^ (r&7) (G4 swizzle); linear-dest gload_lds with
// inverse-swizzled SOURCE addresses (rule #21).
// ---------------------------------------------------------------------------
template <int MODE>
__global__ __launch_bounds__(512, 2) void fgemm_kernel(
    const ushort_t* __restrict__ Ahi, const ushort_t* __restrict__ Alo,
    const ushort_t* __restrict__ Bhi, const ushort_t* __restrict__ Blo,
    const float* __restrict__ bias,
    const int* __restrict__ routed_tok, const float* __restrict__ routed_w,
    const int* __restrict__ counts,
    ushort_t* __restrict__ Ohi, ushort_t* __restrict__ Olo,
    float* __restrict__ outf,
    int e0, int K, int Ntot, int hfull) {
  const int e = e0 + blockIdx.z;
  const int hz = hfull ? blockIdx.z : 0;
  const int count = counts[e];
  const int row0 = blockIdx.y * 128;
  if (row0 >= count) return;
  const int col0 = blockIdx.x * 256;

  __shared__ __align__(16) char lds[49152];
  char* ldsA = lds;             // 16 KB: 128 rows x 128 B
  char* ldsB = lds + 16384;     // 32 KB: 256 cols x 128 B

  const int t = threadIdx.x;
  const int lane = t & 63;
  const int wid = t >> 6;
  const int wr = wid >> 2, wc = wid & 3;
  const int fr = lane & 15, ko = lane >> 4;

  // staging source pointers (advance by 32 bf16 per K-step)
  const ushort_t* srcA[2];
  const ushort_t* srcB[4];
#pragma unroll
  for (int c = 0; c < 2; ++c) {
    int ci = t + 512 * c;             // A chunk 0..1023
    int r = ci >> 3, bp = ci & 7;
    int bs = bp ^ (r & 7);            // logical chunk: 0-3 hi, 4-7 lo
    size_t arow;
    if (MODE == 1) {
      int rr = row0 + r;
      arow = (size_t)routed_tok[e * NCAP + (rr < count ? rr : 0)];
    } else {
      arow = (size_t)hz * NCAP + row0 + r;
    }
    srcA[c] = (bs < 4 ? Ahi : Alo) + arow * (size_t)K + (bs & 3) * 8;
  }
#pragma unroll
  for (int c = 0; c < 4; ++c) {
    int ci = t + 512 * c;             // B chunk 0..2047
    int cc = ci >> 3, bp = ci & 7;
    int bs = bp ^ (cc & 7);
    srcB[c] = (bs < 4 ? Bhi : Blo) +
              ((size_t)e * Ntot + col0 + cc) * (size_t)K + (bs & 3) * 8;
  }

  f32x4 acc[4][4] = {};

  for (int ks = 0; ks < K; ks += 32) {
#pragma unroll
    for (int c = 0; c < 2; ++c) {
      gl_lds16(srcA[c], ldsA + (c * 512 + wid * 64) * 16);
      srcA[c] += 32;
    }
#pragma unroll
    for (int c = 0; c < 4; ++c) {
      gl_lds16(srcB[c], ldsB + (c * 512 + wid * 64) * 16);
      srcB[c] += 32;
    }
    __syncthreads();  // compiler drains vmcnt before s_barrier

    bf16x8 Ah[4], Al[4], Bh[4], Bl[4];
#pragma unroll
    for (int fi = 0; fi < 4; ++fi) {
      int r = wr * 64 + fi * 16 + fr;
      Ah[fi] = *(const bf16x8*)(ldsA + r * 128 + ((ko ^ (r & 7)) << 4));
      Al[fi] = *(const bf16x8*)(ldsA + r * 128 + (((4 + ko) ^ (r & 7)) << 4));
    }
#pragma unroll
    for (int fj = 0; fj < 4; ++fj) {
      int cc = wc * 64 + fj * 16 + fr;
      Bh[fj] = *(const bf16x8*)(ldsB + cc * 128 + ((ko ^ (cc & 7)) << 4));
      Bl[fj] = *(const bf16x8*)(ldsB + cc * 128 + (((4 + ko) ^ (cc & 7)) << 4));
    }
#pragma unroll
    for (int fi = 0; fi < 4; ++fi)
#pragma unroll
      for (int fj = 0; fj < 4; ++fj) {
        acc[fi][fj] = __builtin_amdgcn_mfma_f32_16x16x32_bf16(
            Ah[fi], Bh[fj], acc[fi][fj], 0, 0, 0);
        acc[fi][fj] = __builtin_amdgcn_mfma_f32_16x16x32_bf16(
            Ah[fi], Bl[fj], acc[fi][fj], 0, 0, 0);
        acc[fi][fj] = __builtin_amdgcn_mfma_f32_16x16x32_bf16(
            Al[fi], Bh[fj], acc[fi][fj], 0, 0, 0);
      }
    __syncthreads();
  }

  // C/D layout (m89-verified): col = lane&15 (=fr), row = (lane>>4)*4 + reg
  float bv[4];
#pragma unroll
  for (int fj = 0; fj < 4; ++fj)
    bv[fj] = bias[(size_t)e * Ntot + col0 + wc * 64 + fj * 16 + fr];

  if (MODE == 1) {
#pragma unroll
    for (int fi = 0; fi < 4; ++fi) {
#pragma unroll
      for (int rg = 0; rg < 4; ++rg) {
        int rr = row0 + wr * 64 + fi * 16 + ko * 4 + rg;
        if (rr < count) {
          size_t rb = ((size_t)hz * NCAP + rr) * (size_t)Ntot;
#pragma unroll
          for (int fj = 0; fj < 4; ++fj) {
            int cc = col0 + wc * 64 + fj * 16 + fr;
            float g = gelu_exact(acc[fi][fj][rg] + bv[fj]);
            unsigned short h = f2bf(g);
            Ohi[rb + cc] = h;
            Olo[rb + cc] = f2bf(g - bf2f(h));
          }
        }
      }
    }
  } else {
#pragma unroll
    for (int fi = 0; fi < 4; ++fi) {
#pragma unroll
      for (int rg = 0; rg < 4; ++rg) {
        int rr = row0 + wr * 64 + fi * 16 + ko * 4 + rg;
        if (rr < count) {
          int tok = routed_tok[e * NCAP + rr];
          float wgt = routed_w[e * NCAP + rr];
          float* orow = outf + (size_t)tok * ND;
#pragma unroll
          for (int fj = 0; fj < 4; ++fj) {
            int cc = col0 + wc * 64 + fj * 16 + fr;
            atomicAdd(orow + cc, wgt * (acc[fi][fj][rg] + bv[fj]));
          }
        }
      }
    }
  }
}

// ---------------------------------------------------------------------------
// fp32 fallback GEMMs (proven this round; used if ws too small for fast path)
// ---------------------------------------------------------------------------
__global__ __launch_bounds__(256) void gemm1_kernel(
    const float* __restrict__ x, const float* __restrict__ W1,
    const float* __restrict__ b1, const int* __restrict__ routed_tok,
    const int* __restrict__ counts, float* __restrict__ H,
    int e0, size_t h_stride) {
  const int e = e0 + blockIdx.z;
  const int count = counts[e];
  const int row0 = blockIdx.y * 128;
  if (row0 >= count) return;
  const int col0 = blockIdx.x * 128;
  const float* W = W1 + (size_t)e * ND * NDFF;
  float* Hb = H + (size_t)blockIdx.z * h_stride;

  __shared__ __align__(16) float As[16][128];
  __shared__ __align__(16) float Bs[16][128];

  const int tid = threadIdx.x;
  const int arow = tid >> 1;
  const int aq = (tid & 1) * 8;
  const int r = row0 + arow;
  const int tok = routed_tok[e * NCAP + (r < count ? r : 0)];
  const float* Arow = x + (size_t)tok * ND;
  const int bk = tid >> 5;
  const int bc = (tid & 31) * 4;
  const int ty = tid >> 4, tx = tid & 15;

  float c[8][8] = {};

  for (int k0 = 0; k0 < ND; k0 += 16) {
    float4 av0 = *(const float4*)(Arow + k0 + aq);
    float4 av1 = *(const float4*)(Arow + k0 + aq + 4);
    float4 bv0 = *(const float4*)(W + (size_t)(k0 + bk) * NDFF + col0 + bc);
    float4 bv1 = *(const float4*)(W + (size_t)(k0 + bk + 8) * NDFF + col0 + bc);
    __syncthreads();
    As[aq + 0][arow] = av0.x; As[aq + 1][arow] = av0.y;
    As[aq + 2][arow] = av0.z; As[aq + 3][arow] = av0.w;
    As[aq + 4][arow] = av1.x; As[aq + 5][arow] = av1.y;
    As[aq + 6][arow] = av1.z; As[aq + 7][arow] = av1.w;
    *(float4*)&Bs[bk][bc] = bv0;
    *(float4*)&Bs[bk + 8][bc] = bv1;
    __syncthreads();
#pragma unroll
    for (int kk = 0; kk < 16; ++kk) {
      float4 a0 = *(const float4*)&As[kk][ty * 4];
      float4 a1 = *(const float4*)&As[kk][ty * 4 + 64];
      float4 b0 = *(const float4*)&Bs[kk][tx * 4];
      float4 b1r = *(const float4*)&Bs[kk][tx * 4 + 64];
      float ar[8] = {a0.x, a0.y, a0.z, a0.w, a1.x, a1.y, a1.z, a1.w};
      float br[8] = {b0.x, b0.y, b0.z, b0.w, b1r.x, b1r.y, b1r.z, b1r.w};
#pragma unroll
      for (int i = 0; i < 8; ++i)
#pragma unroll
        for (int j = 0; j < 8; ++j)
          c[i][j] = fmaf(ar[i], br[j], c[i][j]);
    }
  }

  const float* b1e = b1 + (size_t)e * NDFF + col0;
#pragma unroll
  for (int i = 0; i < 8; ++i) {
    int rr = row0 + ty * 4 + (i & 3) + (i >> 2) * 64;
    if (rr < count) {
      float* Hr = Hb + (size_t)rr * NDFF + col0;
      float4 v0, v1;
      v0.x = gelu_exact(c[i][0] + b1e[tx * 4 + 0]);
      v0.y = gelu_exact(c[i][1] + b1e[tx * 4 + 1]);
      v0.z = gelu_exact(c[i][2] + b1e[tx * 4 + 2]);
      v0.w = gelu_exact(c[i][3] + b1e[tx * 4 + 3]);
      v1.x = gelu_exact(c[i][4] + b1e[tx * 4 + 64]);
      v1.y = gelu_exact(c[i][5] + b1e[tx * 4 + 65]);
      v1.z = gelu_exact(c[i][6] + b1e[tx * 4 + 66]);
      v1.w = gelu_exact(c[i][7] + b1e[tx * 4 + 67]);
      *(float4*)(Hr + tx * 4) = v0;
      *(float4*)(Hr + tx * 4 + 64) = v1;
    }
  }
}

__global__ __launch_bounds__(256) void gemm2_kernel(
    const float* __restrict__ H, const float* __restrict__ W2,
    const float* __restrict__ b2, const int* __restrict__ routed_tok,
    const float* __restrict__ routed_w, const int* __restrict__ counts,
    float* __restrict__ out, int e0, size_t h_stride) {
  const int e = e0 + blockIdx.z;
  const int count = counts[e];
  const int row0 = blockIdx.y * 128;
  if (row0 >= count) return;
  const int col0 = blockIdx.x * 128;
  const float* W = W2 + (size_t)e * NDFF * ND;
  const float* Hb = H + (size_t)blockIdx.z * h_stride;

  __shared__ __align__(16) float As[16][128];
  __shared__ __align__(16) float Bs[16][128];

  const int tid = threadIdx.x;
  const int arow = tid >> 1;
  const int aq = (tid & 1) * 8;
  const float* Arow = Hb + (size_t)(row0 + arow) * NDFF;
  const int bk = tid >> 5;
  const int bc = (tid & 31) * 4;
  const int ty = tid >> 4, tx = tid & 15;

  float c[8][8] = {};

  for (int k0 = 0; k0 < NDFF; k0 += 16) {
    float4 av0 = *(const float4*)(Arow + k0 + aq);
    float4 av1 = *(const float4*)(Arow + k0 + aq + 4);
    float4 bv0 = *(const float4*)(W + (size_t)(k0 + bk) * ND + col0 + bc);
    float4 bv1 = *(const float4*)(W + (size_t)(k0 + bk + 8) * ND + col0 + bc);
    __syncthreads();
    As[aq + 0][arow] = av0.x; As[aq + 1][arow] = av0.y;
    As[aq + 2][arow] = av0.z; As[aq + 3][arow] = av0.w;
    As[aq + 4][arow] = av1.x; As[aq + 5][arow] = av1.y;
    As[aq + 6][arow] = av1.z; As[aq + 7][arow] = av1.w;
    *(float4*)&Bs[bk][bc] = bv0;
    *(float4*)&Bs[bk + 8][bc] = bv1;
    __syncthreads();
#pragma unroll
    for (int kk = 0; kk < 16; ++kk) {
      float4 a0 = *(const float4*)&As[kk][ty * 4];
      float4 a1 = *(const float4*)&As[kk][ty * 4 + 64];
      float4 b0 = *(const float4*)&Bs[kk][tx * 4];
      float4 b1r = *(const float4*)&Bs[kk][tx * 4 + 64];
      float ar[8] = {a0.x, a0.y, a0.z, a0.w, a1.x, a1.y, a1.z, a1.w};
      float br[8] = {b0.x, b0.y, b0.z, b0.w, b1r.x, b1r.y, b1r.z, b1r.w};
#pragma unroll
      for (int i = 0; i < 8; ++i)
#pragma unroll
        for (int j = 0; j < 8; ++j)
          c[i][j] = fmaf(ar[i], br[j], c[i][j]);
    }
  }

  const float* b2e = b2 + (size_t)e * ND + col0;
#pragma unroll
  for (int i = 0; i < 8; ++i) {
    int rr = row0 + ty * 4 + (i & 3) + (i >> 2) * 64;
    if (rr < count) {
      int tok = routed_tok[e * NCAP + rr];
      float wgt = routed_w[e * NCAP + rr];
      float* orow = out + (size_t)tok * ND + col0;
#pragma unroll
      for (int j = 0; j < 8; ++j) {
        int cc = tx * 4 + (j & 3) + (j >> 2) * 64;
        atomicAdd(orow + cc, wgt * (c[i][j] + b2e[cc]));
      }
    }
  }
}

// ---------------------------------------------------------------------------
extern "C" void kernel_launch(void* const* d_in, const int* in_sizes, int n_in,
                              void* d_out, int out_size, void* d_ws, size_t ws_size,
                              hipStream_t stream) {
  const float* x  = (const float*)d_in[0];
  const float* gw = (const float*)d_in[1];
  const float* W1 = (const float*)d_in[2];
  const float* b1 = (const float*)d_in[3];
  const float* W2 = (const float*)d_in[4];
  const float* b2 = (const float*)d_in[5];
  float* out = (float*)d_out;

  char* p = (char*)d_ws;
  auto alloc = [&](size_t bytes) -> char* {
    char* q = p;
    p += (bytes + 255) & ~(size_t)255;
    return q;
  };

  int*   top_i = (int*)alloc((size_t)NN * NK * 4);
  float* dispw = (float*)alloc((size_t)NN * NK * 4);
  int*   rtok  = (int*)alloc((size_t)NE * NCAP * 4);
  float* rw    = (float*)alloc((size_t)NE * NCAP * 4);
  int*   counts = (int*)alloc(256);
  float* psum  = (float*)alloc(64);      // psum(32B) + fcnt(32B) contiguous
  int*   fcnt  = (int*)((char*)psum + 32);
  char*  p_base = p;
  const size_t base_used = (size_t)(p - (char*)d_ws);

  const size_t sx = (size_t)NN * ND * 2;              // 16.8 MB per array
  const size_t sw = (size_t)NE * ND * NDFF * 2;       // 33.6 MB per array
  const size_t sHfull = (size_t)NE * NCAP * NDFF * 2; // 84 MB per array
  const size_t sHpe = (size_t)NCAP * NDFF * 2;        // 10.5 MB per array
  const size_t need_fast_pe   = base_used + 2 * sx + 4 * sw + 2 * sHpe + 8192;
  const size_t need_fast_full = base_used + 2 * sx + 4 * sw + 2 * sHfull + 8192;
  const size_t need_old_full  = base_used + (size_t)NE * NCAP * NDFF * 4 + 8192;

  hipMemsetAsync(out, 0, (size_t)NN * ND * 4, stream);
  hipMemsetAsync(psum, 0, 64, stream);

  router_kernel<<<NN / 4, 256, 0, stream>>>(x, gw, top_i, dispw, psum, fcnt);
  scan_kernel<<<1, 512, 0, stream>>>(top_i, dispw, rtok, rw, counts, psum, fcnt,
                                     out + (size_t)NN * ND);

  if (ws_size >= need_fast_pe) {
    // ---------------- split-bf16 MFMA path ----------------
    const bool full = (ws_size >= need_fast_full);
    ushort_t* xhi = (ushort_t*)alloc(sx);
    ushort_t* xlo = (ushort_t*)alloc(sx);
    ushort_t* wt1hi = (ushort_t*)alloc(sw);
    ushort_t* wt1lo = (ushort_t*)alloc(sw);
    ushort_t* wt2hi = (ushort_t*)alloc(sw);
    ushort_t* wt2lo = (ushort_t*)alloc(sw);
    ushort_t* Hhi = (ushort_t*)alloc(full ? sHfull : sHpe);
    ushort_t* Hlo = (ushort_t*)alloc(full ? sHfull : sHpe);

    splitx_kernel<<<(NN * ND / 4) / 256, 256, 0, stream>>>(x, xhi, xlo);
    tsplit_kernel<<<dim3(NDFF / 32, ND / 32, NE), 256, 0, stream>>>(
        W1, wt1hi, wt1lo, ND, NDFF);
    tsplit_kernel<<<dim3(ND / 32, NDFF / 32, NE), 256, 0, stream>>>(
        W2, wt2hi, wt2lo, NDFF, ND);

    if (full) {
      fgemm_kernel<1><<<dim3(NDFF / 256, NCAP / 128, NE), 512, 0, stream>>>(
          xhi, xlo, wt1hi, wt1lo, b1, rtok, rw, counts, Hhi, Hlo, nullptr,
          0, ND, NDFF, 1);
      fgemm_kernel<2><<<dim3(ND / 256, NCAP / 128, NE), 512, 0, stream>>>(
          Hhi, Hlo, wt2hi, wt2lo, b2, rtok, rw, counts, nullptr, nullptr, out,
          0, NDFF, ND, 1);
    } else {
      for (int e = 0; e < NE; ++e) {
        fgemm_kernel<1><<<dim3(NDFF / 256, NCAP / 128, 1), 512, 0, stream>>>(
            xhi, xlo, wt1hi, wt1lo, b1, rtok, rw, counts, Hhi, Hlo, nullptr,
            e, ND, NDFF, 0);
        fgemm_kernel<2><<<dim3(ND / 256, NCAP / 128, 1), 512, 0, stream>>>(
            Hhi, Hlo, wt2hi, wt2lo, b2, rtok, rw, counts, nullptr, nullptr, out,
            e, NDFF, ND, 0);
      }
    }
  } else {
    // ---------------- fp32 vector fallback (proven) ----------------
    p = p_base;
    float* H = (float*)p;
    const bool fullH = (ws_size >= need_old_full);
    if (fullH) {
      gemm1_kernel<<<dim3(NDFF / 128, NCAP / 128, NE), 256, 0, stream>>>(
          x, W1, b1, rtok, counts, H, 0, (size_t)NCAP * NDFF);
      gemm2_kernel<<<dim3(ND / 128, NCAP / 128, NE), 256, 0, stream>>>(
          H, W2, b2, rtok, rw, counts, out, 0, (size_t)NCAP * NDFF);
    } else {
      for (int e = 0; e < NE; ++e) {
        gemm1_kernel<<<dim3(NDFF / 128, NCAP / 128, 1), 256, 0, stream>>>(
            x, W1, b1, rtok, counts, H, e, 0);
        gemm2_kernel<<<dim3(ND / 128, NCAP / 128, 1), 256, 0, stream>>>(
            H, W2, b2, rtok, rw, counts, out, e, 0);
      }
    }
  }
}

// Round 11
// 1084.998 us; speedup vs baseline: 1.8381x; 1.6525x over previous
//
#include <hip/hip_runtime.h>
#include <hip/hip_bf16.h>
#include <math.h>

// Problem constants (from reference)
#define NB   2
#define NT   4096
#define ND   1024
#define NDFF 2048
#define NE   8
#define NK   2
#define NN   (NB * NT)   // 8192 tokens
#define NCAP 2560        // ceil(1.25 * NN * NK / NE)

typedef unsigned short ushort_t;
typedef __attribute__((ext_vector_type(8))) short bf16x8;   // 8 bf16 = 4 VGPRs
typedef __attribute__((ext_vector_type(8))) unsigned short u16x8;
typedef __attribute__((ext_vector_type(4))) float f32x4;

__device__ __forceinline__ float gelu_exact(float v) {
  return 0.5f * v * (1.0f + erff(v * 0.70710678118654752f));
}

// f32 -> bf16 round-to-nearest-even
__device__ __forceinline__ unsigned short f2bf(float f) {
  unsigned int u = __float_as_uint(f);
  u += 0x7fffu + ((u >> 16) & 1u);
  return (unsigned short)(u >> 16);
}
__device__ __forceinline__ float bf2f(unsigned short h) {
  return __uint_as_float(((unsigned int)h) << 16);
}

// async global->LDS, 16B per lane (lane i writes lds_base + i*16)
__device__ __forceinline__ void gl_lds16(const void* g, void* l) {
  __builtin_amdgcn_global_load_lds(
      (__attribute__((address_space(1))) void*)g,
      (__attribute__((address_space(3))) void*)l, 16, 0, 0);
}

// ---------------------------------------------------------------------------
// Router (proven)
// ---------------------------------------------------------------------------
__global__ __launch_bounds__(256) void router_kernel(
    const float* __restrict__ x, const float* __restrict__ gw,
    int* __restrict__ top_i, float* __restrict__ disp_w,
    float* __restrict__ p_sum, int* __restrict__ f_cnt) {
  __shared__ float s_p[NE];
  __shared__ int s_f[NE];
  if (threadIdx.x < NE) { s_p[threadIdx.x] = 0.0f; s_f[threadIdx.x] = 0; }
  __syncthreads();

  const int lane = threadIdx.x & 63;
  const int wv = threadIdx.x >> 6;
  const int n = blockIdx.x * 4 + wv;

  const float4* xr = (const float4*)(x + (size_t)n * ND);
  float acc[NE];
#pragma unroll
  for (int e = 0; e < NE; ++e) acc[e] = 0.0f;

#pragma unroll
  for (int q = 0; q < 4; ++q) {
    float4 xv = xr[lane * 4 + q];
#pragma unroll
    for (int e = 0; e < NE; ++e) {
      float4 g = ((const float4*)(gw + (size_t)e * ND))[lane * 4 + q];
      acc[e] += xv.x * g.x + xv.y * g.y + xv.z * g.z + xv.w * g.w;
    }
  }
#pragma unroll
  for (int m = 1; m < 64; m <<= 1) {
#pragma unroll
    for (int e = 0; e < NE; ++e) acc[e] += __shfl_xor(acc[e], m, 64);
  }

  float mx = acc[0];
#pragma unroll
  for (int e = 1; e < NE; ++e) mx = fmaxf(mx, acc[e]);
  float p[NE];
  float s = 0.0f;
#pragma unroll
  for (int e = 0; e < NE; ++e) { p[e] = expf(acc[e] - mx); s += p[e]; }
  float inv = 1.0f / s;
#pragma unroll
  for (int e = 0; e < NE; ++e) p[e] *= inv;

  int i1 = 0; float v1 = p[0];
#pragma unroll
  for (int e = 1; e < NE; ++e) { if (p[e] > v1) { v1 = p[e]; i1 = e; } }
  int i2 = 0; float v2 = -1.0f;
#pragma unroll
  for (int e = 0; e < NE; ++e) { if (e != i1 && p[e] > v2) { v2 = p[e]; i2 = e; } }

  if (lane == 0) {
    float dsum = v1 + v2 + 1e-9f;
    top_i[n * NK + 0] = i1;
    top_i[n * NK + 1] = i2;
    disp_w[n * NK + 0] = v1 / dsum;
    disp_w[n * NK + 1] = v2 / dsum;
#pragma unroll
    for (int e = 0; e < NE; ++e) atomicAdd(&s_p[e], p[e]);
    atomicAdd(&s_f[i1], 1);
    atomicAdd(&s_f[i2], 1);
  }
  __syncthreads();
  if (threadIdx.x < NE) {
    atomicAdd(&p_sum[threadIdx.x], s_p[threadIdx.x]);
    atomicAdd(&f_cnt[threadIdx.x], s_f[threadIdx.x]);
  }
}

// ---------------------------------------------------------------------------
// Capacity scan (proven)
// ---------------------------------------------------------------------------
__global__ __launch_bounds__(512) void scan_kernel(
    const int* __restrict__ top_i, const float* __restrict__ disp_w,
    int* __restrict__ routed_tok, float* __restrict__ routed_w,
    int* __restrict__ counts, const float* __restrict__ p_sum,
    const int* __restrict__ f_cnt, float* __restrict__ aux_out) {
  __shared__ __align__(16) int s_top[NN * NK];
  for (int i = threadIdx.x; i < (NN * NK) / 4; i += 512)
    ((int4*)s_top)[i] = ((const int4*)top_i)[i];
  __syncthreads();

  const int e = threadIdx.x >> 6;
  const int lane = threadIdx.x & 63;
  int cnt = 0;
  for (int c = 0; c < (NN * NK) / 64; ++c) {
    int a = c * 64 + lane;
    int n = a & (NN - 1);
    int k = a >> 13;
    bool m = (s_top[n * NK + k] == e);
    unsigned long long mask = __ballot(m);
    if (m) {
      int pos = cnt + __popcll(mask & ((1ull << lane) - 1ull));
      if (pos < NCAP) {
        routed_tok[e * NCAP + pos] = n;
        routed_w[e * NCAP + pos] = disp_w[n * NK + k];
      }
    }
    cnt += (int)__popcll(mask);
  }
  if (lane == 0) counts[e] = (cnt < NCAP) ? cnt : NCAP;

  if (threadIdx.x == 0) {
    float aux = 0.0f;
    for (int j = 0; j < NE; ++j)
      aux += (p_sum[j] / (float)NN) * ((float)f_cnt[j] / (float)NN);
    aux_out[0] = aux * (float)NE;
  }
}

// ---------------------------------------------------------------------------
// tsplit: W [E][K][N] f32 -> T [E][N][K] bf16 hi/lo (32x32 LDS transpose)
// ---------------------------------------------------------------------------
__global__ __launch_bounds__(256) void tsplit_kernel(
    const float* __restrict__ W, ushort_t* __restrict__ Thi,
    ushort_t* __restrict__ Tlo, int K, int N) {
  __shared__ float tile[32][33];
  const int t = threadIdx.x;
  const int n0 = blockIdx.x * 32, k0 = blockIdx.y * 32;
  const int r = t >> 3, c4 = (t & 7) * 4;
  float4 v = *(const float4*)(W + (size_t)blockIdx.z * K * N +
                              (size_t)(k0 + r) * N + n0 + c4);
  tile[r][c4 + 0] = v.x; tile[r][c4 + 1] = v.y;
  tile[r][c4 + 2] = v.z; tile[r][c4 + 3] = v.w;
  __syncthreads();
  const int n = t >> 3, kc = (t & 7) * 4;
  ushort4 h, l;
  float f;
  f = tile[kc + 0][n]; h.x = f2bf(f); l.x = f2bf(f - bf2f(h.x));
  f = tile[kc + 1][n]; h.y = f2bf(f); l.y = f2bf(f - bf2f(h.y));
  f = tile[kc + 2][n]; h.z = f2bf(f); l.z = f2bf(f - bf2f(h.z));
  f = tile[kc + 3][n]; h.w = f2bf(f); l.w = f2bf(f - bf2f(h.w));
  size_t o = (size_t)blockIdx.z * N * K + (size_t)(n0 + n) * K + k0 + kc;
  *(ushort4*)(Thi + o) = h;
  *(ushort4*)(Tlo + o) = l;
}

// ---------------------------------------------------------------------------
// fgemm_fused: split-bf16 MFMA GEMM, 128x256 tile, 8 waves, BK=32, KLOOP=1024.
// Role by blockIdx.z: z < n_g1_z -> G1 (expert z): H[chunk] = gelu(x@W1+b1),
//   A reg-staged from f32 x (split in-register, ds_write to swizzled slots).
// else -> G2 (expert z-n_g1_z): out += w*(H[chunk]@W2+b2), split-K2 via
//   blockIdx.x>>2 (bias only on kseg 0), A via global_load_lds from split H.
// LDS layout/swizzle and MFMA sequence identical to the round-5-verified code.
// ---------------------------------------------------------------------------
__global__ __launch_bounds__(512, 2) void fgemm_fused(
    const float* __restrict__ x,
    const ushort_t* __restrict__ w1hi, const ushort_t* __restrict__ w1lo,
    const float* __restrict__ b1,
    const ushort_t* __restrict__ w2hi, const ushort_t* __restrict__ w2lo,
    const float* __restrict__ b2,
    const ushort_t* __restrict__ Hrhi, const ushort_t* __restrict__ Hrlo,
    ushort_t* __restrict__ Hwhi, ushort_t* __restrict__ Hwlo,
    const int* __restrict__ routed_tok, const float* __restrict__ routed_w,
    const int* __restrict__ counts, float* __restrict__ outf,
    int n_g1_z, int g1_lo, int g2_lo, int Rh) {
  const int bz = blockIdx.z;
  const bool isG1 = bz < n_g1_z;
  const int e = isG1 ? bz : bz - n_g1_z;
  const int count = counts[e];
  const int chunk_lo = isG1 ? g1_lo : g2_lo;
  const int local0 = blockIdx.y * 128;
  const int row0 = chunk_lo + local0;
  if (row0 >= count) return;
  const int bx = blockIdx.x;
  const int col0 = isG1 ? bx * 256 : (bx & 3) * 256;
  const int koff = isG1 ? 0 : (bx >> 2) * 1024;
  const int Ntot = isG1 ? NDFF : ND;
  const int Bstride = isG1 ? ND : NDFF;   // K-length of B rows

  __shared__ __align__(16) char lds[49152];
  char* ldsA = lds;             // 16 KB: 128 rows x 8 chunks x 16B
  char* ldsB = lds + 16384;     // 32 KB: 256 cols x 8 chunks x 16B

  const int t = threadIdx.x;
  const int lane = t & 63;
  const int wid = t >> 6;
  const int wr = wid >> 2, wc = wid & 3;
  const int fr = lane & 15, ko = lane >> 4;

  // ---- A staging setup ----
  const float* srcAf = nullptr;   // G1: f32 x row segment
  char* dstH_ = nullptr; char* dstL_ = nullptr;
  const ushort_t* srcA[2];        // G2: split-H gload_lds sources
  if (isG1) {
    const int r = t >> 2, kc = t & 3;
    const int rr = row0 + r;
    const int tok = routed_tok[e * NCAP + (rr < count ? rr : 0)];
    srcAf = x + (size_t)tok * ND + kc * 8;
    dstH_ = ldsA + (size_t)(r * 8 + (kc ^ (r & 7))) * 16;
    dstL_ = ldsA + (size_t)(r * 8 + ((kc + 4) ^ (r & 7))) * 16;
  } else {
#pragma unroll
    for (int c = 0; c < 2; ++c) {
      int ci = t + 512 * c;
      int r = ci >> 3, bp = ci & 7;
      int bs = bp ^ (r & 7);
      size_t arow = (size_t)e * Rh + local0 + r;
      srcA[c] = (bs < 4 ? Hrhi : Hrlo) + arow * (size_t)NDFF + koff + (bs & 3) * 8;
    }
  }
  // ---- B staging setup ----
  const ushort_t* Bh = isG1 ? w1hi : w2hi;
  const ushort_t* Bl = isG1 ? w1lo : w2lo;
  const ushort_t* srcB[4];
#pragma unroll
  for (int c = 0; c < 4; ++c) {
    int ci = t + 512 * c;
    int cc = ci >> 3, bp = ci & 7;
    int bs = bp ^ (cc & 7);
    srcB[c] = (bs < 4 ? Bh : Bl) +
              ((size_t)e * Ntot + col0 + cc) * (size_t)Bstride + koff + (bs & 3) * 8;
  }

  f32x4 acc[4][4] = {};

  for (int ks = 0; ks < 1024; ks += 32) {
    if (isG1) {
      float4 v0 = *(const float4*)(srcAf);
      float4 v1 = *(const float4*)(srcAf + 4);
      srcAf += 32;
      u16x8 hh, ll;
      unsigned short h; float f;
      f = v0.x; h = f2bf(f); hh[0] = h; ll[0] = f2bf(f - bf2f(h));
      f = v0.y; h = f2bf(f); hh[1] = h; ll[1] = f2bf(f - bf2f(h));
      f = v0.z; h = f2bf(f); hh[2] = h; ll[2] = f2bf(f - bf2f(h));
      f = v0.w; h = f2bf(f); hh[3] = h; ll[3] = f2bf(f - bf2f(h));
      f = v1.x; h = f2bf(f); hh[4] = h; ll[4] = f2bf(f - bf2f(h));
      f = v1.y; h = f2bf(f); hh[5] = h; ll[5] = f2bf(f - bf2f(h));
      f = v1.z; h = f2bf(f); hh[6] = h; ll[6] = f2bf(f - bf2f(h));
      f = v1.w; h = f2bf(f); hh[7] = h; ll[7] = f2bf(f - bf2f(h));
      *(u16x8*)dstH_ = hh;
      *(u16x8*)dstL_ = ll;
    } else {
#pragma unroll
      for (int c = 0; c < 2; ++c) {
        gl_lds16(srcA[c], ldsA + (c * 512 + wid * 64) * 16);
        srcA[c] += 32;
      }
    }
#pragma unroll
    for (int c = 0; c < 4; ++c) {
      gl_lds16(srcB[c], ldsB + (c * 512 + wid * 64) * 16);
      srcB[c] += 32;
    }
    __syncthreads();

    bf16x8 Ah[4], Al[4], Bhf[4], Blf[4];
#pragma unroll
    for (int fi = 0; fi < 4; ++fi) {
      int r = wr * 64 + fi * 16 + fr;
      Ah[fi] = *(const bf16x8*)(ldsA + r * 128 + ((ko ^ (r & 7)) << 4));
      Al[fi] = *(const bf16x8*)(ldsA + r * 128 + (((4 + ko) ^ (r & 7)) << 4));
    }
#pragma unroll
    for (int fj = 0; fj < 4; ++fj) {
      int cc = wc * 64 + fj * 16 + fr;
      Bhf[fj] = *(const bf16x8*)(ldsB + cc * 128 + ((ko ^ (cc & 7)) << 4));
      Blf[fj] = *(const bf16x8*)(ldsB + cc * 128 + (((4 + ko) ^ (cc & 7)) << 4));
    }
#pragma unroll
    for (int fi = 0; fi < 4; ++fi)
#pragma unroll
      for (int fj = 0; fj < 4; ++fj) {
        acc[fi][fj] = __builtin_amdgcn_mfma_f32_16x16x32_bf16(
            Ah[fi], Bhf[fj], acc[fi][fj], 0, 0, 0);
        acc[fi][fj] = __builtin_amdgcn_mfma_f32_16x16x32_bf16(
            Ah[fi], Blf[fj], acc[fi][fj], 0, 0, 0);
        acc[fi][fj] = __builtin_amdgcn_mfma_f32_16x16x32_bf16(
            Al[fi], Bhf[fj], acc[fi][fj], 0, 0, 0);
      }
    __syncthreads();
  }

  // C/D layout (verified): col = lane&15, row = (lane>>4)*4 + reg
  const float* bias = isG1 ? b1 : b2;
  float bv[4];
#pragma unroll
  for (int fj = 0; fj < 4; ++fj)
    bv[fj] = (koff == 0)
                 ? bias[(size_t)e * Ntot + col0 + wc * 64 + fj * 16 + fr]
                 : 0.0f;

  if (isG1) {
#pragma unroll
    for (int fi = 0; fi < 4; ++fi) {
#pragma unroll
      for (int rg = 0; rg < 4; ++rg) {
        int rr = row0 + wr * 64 + fi * 16 + ko * 4 + rg;
        if (rr < count) {
          size_t rb = ((size_t)e * Rh + (rr - chunk_lo)) * (size_t)NDFF;
#pragma unroll
          for (int fj = 0; fj < 4; ++fj) {
            int cc = col0 + wc * 64 + fj * 16 + fr;
            float g = gelu_exact(acc[fi][fj][rg] + bv[fj]);
            unsigned short hh = f2bf(g);
            Hwhi[rb + cc] = hh;
            Hwlo[rb + cc] = f2bf(g - bf2f(hh));
          }
        }
      }
    }
  } else {
#pragma unroll
    for (int fi = 0; fi < 4; ++fi) {
#pragma unroll
      for (int rg = 0; rg < 4; ++rg) {
        int rr = row0 + wr * 64 + fi * 16 + ko * 4 + rg;
        if (rr < count) {
          int tok = routed_tok[e * NCAP + rr];
          float wgt = routed_w[e * NCAP + rr];
          float* orow = outf + (size_t)tok * ND;
#pragma unroll
          for (int fj = 0; fj < 4; ++fj) {
            int cc = col0 + wc * 64 + fj * 16 + fr;
            atomicAdd(orow + cc, wgt * (acc[fi][fj][rg] + bv[fj]));
          }
        }
      }
    }
  }
}

// ---------------------------------------------------------------------------
// fp32 vector fallback (proven round 4) — only if ws can't fit the fast path
// ---------------------------------------------------------------------------
__global__ __launch_bounds__(256) void gemm1_kernel(
    const float* __restrict__ x, const float* __restrict__ W1,
    const float* __restrict__ b1, const int* __restrict__ routed_tok,
    const int* __restrict__ counts, float* __restrict__ H,
    int e0, size_t h_stride) {
  const int e = e0 + blockIdx.z;
  const int count = counts[e];
  const int row0 = blockIdx.y * 128;
  if (row0 >= count) return;
  const int col0 = blockIdx.x * 128;
  const float* W = W1 + (size_t)e * ND * NDFF;
  float* Hb = H + (size_t)blockIdx.z * h_stride;

  __shared__ __align__(16) float As[16][128];
  __shared__ __align__(16) float Bs[16][128];

  const int tid = threadIdx.x;
  const int arow = tid >> 1;
  const int aq = (tid & 1) * 8;
  const int r = row0 + arow;
  const int tok = routed_tok[e * NCAP + (r < count ? r : 0)];
  const float* Arow = x + (size_t)tok * ND;
  const int bk = tid >> 5;
  const int bc = (tid & 31) * 4;
  const int ty = tid >> 4, tx = tid & 15;

  float c[8][8] = {};

  for (int k0 = 0; k0 < ND; k0 += 16) {
    float4 av0 = *(const float4*)(Arow + k0 + aq);
    float4 av1 = *(const float4*)(Arow + k0 + aq + 4);
    float4 bv0 = *(const float4*)(W + (size_t)(k0 + bk) * NDFF + col0 + bc);
    float4 bv1 = *(const float4*)(W + (size_t)(k0 + bk + 8) * NDFF + col0 + bc);
    __syncthreads();
    As[aq + 0][arow] = av0.x; As[aq + 1][arow] = av0.y;
    As[aq + 2][arow] = av0.z; As[aq + 3][arow] = av0.w;
    As[aq + 4][arow] = av1.x; As[aq + 5][arow] = av1.y;
    As[aq + 6][arow] = av1.z; As[aq + 7][arow] = av1.w;
    *(float4*)&Bs[bk][bc] = bv0;
    *(float4*)&Bs[bk + 8][bc] = bv1;
    __syncthreads();
#pragma unroll
    for (int kk = 0; kk < 16; ++kk) {
      float4 a0 = *(const float4*)&As[kk][ty * 4];
      float4 a1 = *(const float4*)&As[kk][ty * 4 + 64];
      float4 b0 = *(const float4*)&Bs[kk][tx * 4];
      float4 b1r = *(const float4*)&Bs[kk][tx * 4 + 64];
      float ar[8] = {a0.x, a0.y, a0.z, a0.w, a1.x, a1.y, a1.z, a1.w};
      float br[8] = {b0.x, b0.y, b0.z, b0.w, b1r.x, b1r.y, b1r.z, b1r.w};
#pragma unroll
      for (int i = 0; i < 8; ++i)
#pragma unroll
        for (int j = 0; j < 8; ++j)
          c[i][j] = fmaf(ar[i], br[j], c[i][j]);
    }
  }

  const float* b1e = b1 + (size_t)e * NDFF + col0;
#pragma unroll
  for (int i = 0; i < 8; ++i) {
    int rr = row0 + ty * 4 + (i & 3) + (i >> 2) * 64;
    if (rr < count) {
      float* Hr = Hb + (size_t)rr * NDFF + col0;
      float4 v0, v1;
      v0.x = gelu_exact(c[i][0] + b1e[tx * 4 + 0]);
      v0.y = gelu_exact(c[i][1] + b1e[tx * 4 + 1]);
      v0.z = gelu_exact(c[i][2] + b1e[tx * 4 + 2]);
      v0.w = gelu_exact(c[i][3] + b1e[tx * 4 + 3]);
      v1.x = gelu_exact(c[i][4] + b1e[tx * 4 + 64]);
      v1.y = gelu_exact(c[i][5] + b1e[tx * 4 + 65]);
      v1.z = gelu_exact(c[i][6] + b1e[tx * 4 + 66]);
      v1.w = gelu_exact(c[i][7] + b1e[tx * 4 + 67]);
      *(float4*)(Hr + tx * 4) = v0;
      *(float4*)(Hr + tx * 4 + 64) = v1;
    }
  }
}

__global__ __launch_bounds__(256) void gemm2_kernel(
    const float* __restrict__ H, const float* __restrict__ W2,
    const float* __restrict__ b2, const int* __restrict__ routed_tok,
    const float* __restrict__ routed_w, const int* __restrict__ counts,
    float* __restrict__ out, int e0, size_t h_stride) {
  const int e = e0 + blockIdx.z;
  const int count = counts[e];
  const int row0 = blockIdx.y * 128;
  if (row0 >= count) return;
  const int col0 = blockIdx.x * 128;
  const float* W = W2 + (size_t)e * NDFF * ND;
  const float* Hb = H + (size_t)blockIdx.z * h_stride;

  __shared__ __align__(16) float As[16][128];
  __shared__ __align__(16) float Bs[16][128];

  const int tid = threadIdx.x;
  const int arow = tid >> 1;
  const int aq = (tid & 1) * 8;
  const float* Arow = Hb + (size_t)(row0 + arow) * NDFF;
  const int bk = tid >> 5;
  const int bc = (tid & 31) * 4;
  const int ty = tid >> 4, tx = tid & 15;

  float c[8][8] = {};

  for (int k0 = 0; k0 < NDFF; k0 += 16) {
    float4 av0 = *(const float4*)(Arow + k0 + aq);
    float4 av1 = *(const float4*)(Arow + k0 + aq + 4);
    float4 bv0 = *(const float4*)(W + (size_t)(k0 + bk) * ND + col0 + bc);
    float4 bv1 = *(const float4*)(W + (size_t)(k0 + bk + 8) * ND + col0 + bc);
    __syncthreads();
    As[aq + 0][arow] = av0.x; As[aq + 1][arow] = av0.y;
    As[aq + 2][arow] = av0.z; As[aq + 3][arow] = av0.w;
    As[aq + 4][arow] = av1.x; As[aq + 5][arow] = av1.y;
    As[aq + 6][arow] = av1.z; As[aq + 7][arow] = av1.w;
    *(float4*)&Bs[bk][bc] = bv0;
    *(float4*)&Bs[bk + 8][bc] = bv1;
    __syncthreads();
#pragma unroll
    for (int kk = 0; kk < 16; ++kk) {
      float4 a0 = *(const float4*)&As[kk][ty * 4];
      float4 a1 = *(const float4*)&As[kk][ty * 4 + 64];
      float4 b0 = *(const float4*)&Bs[kk][tx * 4];
      float4 b1r = *(const float4*)&Bs[kk][tx * 4 + 64];
      float ar[8] = {a0.x, a0.y, a0.z, a0.w, a1.x, a1.y, a1.z, a1.w};
      float br[8] = {b0.x, b0.y, b0.z, b0.w, b1r.x, b1r.y, b1r.z, b1r.w};
#pragma unroll
      for (int i = 0; i < 8; ++i)
#pragma unroll
        for (int j = 0; j < 8; ++j)
          c[i][j] = fmaf(ar[i], br[j], c[i][j]);
    }
  }

  const float* b2e = b2 + (size_t)e * ND + col0;
#pragma unroll
  for (int i = 0; i < 8; ++i) {
    int rr = row0 + ty * 4 + (i & 3) + (i >> 2) * 64;
    if (rr < count) {
      int tok = routed_tok[e * NCAP + rr];
      float wgt = routed_w[e * NCAP + rr];
      float* orow = out + (size_t)tok * ND + col0;
#pragma unroll
      for (int j = 0; j < 8; ++j) {
        int cc = tx * 4 + (j & 3) + (j >> 2) * 64;
        atomicAdd(orow + cc, wgt * (c[i][j] + b2e[cc]));
      }
    }
  }
}

// ---------------------------------------------------------------------------
extern "C" void kernel_launch(void* const* d_in, const int* in_sizes, int n_in,
                              void* d_out, int out_size, void* d_ws, size_t ws_size,
                              hipStream_t stream) {
  const float* x  = (const float*)d_in[0];
  const float* gw = (const float*)d_in[1];
  const float* W1 = (const float*)d_in[2];
  const float* b1 = (const float*)d_in[3];
  const float* W2 = (const float*)d_in[4];
  const float* b2 = (const float*)d_in[5];
  float* out = (float*)d_out;

  char* p = (char*)d_ws;
  auto alloc = [&](size_t bytes) -> char* {
    char* q = p;
    p += (bytes + 255) & ~(size_t)255;
    return q;
  };

  int*   top_i = (int*)alloc((size_t)NN * NK * 4);
  float* dispw = (float*)alloc((size_t)NN * NK * 4);
  int*   rtok  = (int*)alloc((size_t)NE * NCAP * 4);
  float* rw    = (float*)alloc((size_t)NE * NCAP * 4);
  int*   counts = (int*)alloc(256);
  float* psum  = (float*)alloc(64);
  int*   fcnt  = (int*)((char*)psum + 32);
  char*  p_base = p;

  hipMemsetAsync(out, 0, (size_t)NN * ND * 4, stream);
  hipMemsetAsync(psum, 0, 64, stream);

  router_kernel<<<NN / 4, 256, 0, stream>>>(x, gw, top_i, dispw, psum, fcnt);
  scan_kernel<<<1, 512, 0, stream>>>(top_i, dispw, rtok, rw, counts, psum, fcnt,
                                     out + (size_t)NN * ND);

  // ---- plan the GEMM path from ws_size ----
  const size_t sw = (size_t)NE * ND * NDFF * 2;          // 32 MiB per split array
  const size_t perRow = (size_t)NE * NDFF * 2 * 2;       // 64 KiB per H row slot
  size_t wt_end = (size_t)(p_base - (char*)d_ws) + 4 * (sw + 256);
  size_t avail = (ws_size > wt_end + 8192) ? ws_size - wt_end - 8192 : 0;

  int Rh = 0;
  bool full = false;
  if (avail >= (size_t)NCAP * perRow) {
    full = true; Rh = NCAP;
  } else {
    Rh = (int)((avail / (2 * perRow)) & ~(size_t)127);
    if (Rh > NCAP - 128) Rh = NCAP - 128;
  }

  if (Rh >= 128) {
    // ---------------- split-bf16 MFMA path ----------------
    ushort_t* w1hi = (ushort_t*)alloc(sw);
    ushort_t* w1lo = (ushort_t*)alloc(sw);
    ushort_t* w2hi = (ushort_t*)alloc(sw);
    ushort_t* w2lo = (ushort_t*)alloc(sw);

    tsplit_kernel<<<dim3(NDFF / 32, ND / 32, NE), 256, 0, stream>>>(
        W1, w1hi, w1lo, ND, NDFF);
    tsplit_kernel<<<dim3(ND / 32, NDFF / 32, NE), 256, 0, stream>>>(
        W2, w2hi, w2lo, NDFF, ND);

    const size_t hb = (size_t)NE * Rh * NDFF * 2;
    if (full) {
      ushort_t* Hhi = (ushort_t*)alloc(hb);
      ushort_t* Hlo = (ushort_t*)alloc(hb);
      fgemm_fused<<<dim3(8, NCAP / 128, 8), 512, 0, stream>>>(
          x, w1hi, w1lo, b1, w2hi, w2lo, b2, Hhi, Hlo, Hhi, Hlo,
          rtok, rw, counts, out, 8, 0, 0, Rh);
      fgemm_fused<<<dim3(8, NCAP / 128, 8), 512, 0, stream>>>(
          x, w1hi, w1lo, b1, w2hi, w2lo, b2, Hhi, Hlo, Hhi, Hlo,
          rtok, rw, counts, out, 0, 0, 0, Rh);
    } else {
      ushort_t* h0hi = (ushort_t*)alloc(hb);
      ushort_t* h0lo = (ushort_t*)alloc(hb);
      ushort_t* h1hi = (ushort_t*)alloc(hb);
      ushort_t* h1lo = (ushort_t*)alloc(hb);
      ushort_t* bh[2] = {h0hi, h1hi};
      ushort_t* bl[2] = {h0lo, h1lo};
      const int P = (NCAP + Rh - 1) / Rh;
      const int ylen = Rh / 128;
      // L0: g1(chunk 0)
      fgemm_fused<<<dim3(8, ylen, 8), 512, 0, stream>>>(
          x, w1hi, w1lo, b1, w2hi, w2lo, b2, bh[0], bl[0], bh[0], bl[0],
          rtok, rw, counts, out, 8, 0, 0, Rh);
      // Li: g2(chunk i-1) merged with g1(chunk i)
      for (int i = 1; i < P; ++i) {
        fgemm_fused<<<dim3(8, ylen, 16), 512, 0, stream>>>(
            x, w1hi, w1lo, b1, w2hi, w2lo, b2,
            bh[(i - 1) & 1], bl[(i - 1) & 1], bh[i & 1], bl[i & 1],
            rtok, rw, counts, out, 8, i * Rh, (i - 1) * Rh, Rh);
      }
      // LP: g2(last chunk)
      fgemm_fused<<<dim3(8, ylen, 8), 512, 0, stream>>>(
          x, w1hi, w1lo, b1, w2hi, w2lo, b2,
          bh[(P - 1) & 1], bl[(P - 1) & 1], bh[(P - 1) & 1], bl[(P - 1) & 1],
          rtok, rw, counts, out, 0, 0, (P - 1) * Rh, Rh);
    }
  } else {
    // ---------------- fp32 vector fallback (proven) ----------------
    p = p_base;
    float* H = (float*)p;
    const size_t need_old_full =
        (size_t)(p_base - (char*)d_ws) + (size_t)NE * NCAP * NDFF * 4 + 8192;
    const bool fullH = (ws_size >= need_old_full);
    if (fullH) {
      gemm1_kernel<<<dim3(NDFF / 128, NCAP / 128, NE), 256, 0, stream>>>(
          x, W1, b1, rtok, counts, H, 0, (size_t)NCAP * NDFF);
      gemm2_kernel<<<dim3(ND / 128, NCAP / 128, NE), 256, 0, stream>>>(
          H, W2, b2, rtok, rw, counts, out, 0, (size_t)NCAP * NDFF);
    } else {
      for (int e = 0; e < NE; ++e) {
        gemm1_kernel<<<dim3(NDFF / 128, NCAP / 128, 1), 256, 0, stream>>>(
            x, W1, b1, rtok, counts, H, e, 0);
        gemm2_kernel<<<dim3(ND / 128, NCAP / 128, 1), 256, 0, stream>>>(
            H, W2, b2, rtok, rw, counts, out, e, 0);
      }
    }
  }
}

// Round 12
// 967.084 us; speedup vs baseline: 2.0622x; 1.1219x over previous
//
#include <hip/hip_runtime.h>
#include <hip/hip_bf16.h>
#include <math.h>

// Problem constants (from reference)
#define NB   2
#define NT   4096
#define ND   1024
#define NDFF 2048
#define NE   8
#define NK   2
#define NN   (NB * NT)   // 8192 tokens
#define NCAP 2560        // ceil(1.25 * NN * NK / NE)

typedef unsigned short ushort_t;
typedef __attribute__((ext_vector_type(8))) short bf16x8;   // 8 bf16 = 4 VGPRs
typedef __attribute__((ext_vector_type(8))) unsigned short u16x8;
typedef __attribute__((ext_vector_type(4))) float f32x4;

__device__ __forceinline__ float gelu_exact(float v) {
  return 0.5f * v * (1.0f + erff(v * 0.70710678118654752f));
}

// f32 -> bf16 round-to-nearest-even
__device__ __forceinline__ unsigned short f2bf(float f) {
  unsigned int u = __float_as_uint(f);
  u += 0x7fffu + ((u >> 16) & 1u);
  return (unsigned short)(u >> 16);
}
__device__ __forceinline__ float bf2f(unsigned short h) {
  return __uint_as_float(((unsigned int)h) << 16);
}

// async global->LDS, 16B per lane (lane i writes lds_base + i*16)
__device__ __forceinline__ void gl_lds16(const void* g, void* l) {
  __builtin_amdgcn_global_load_lds(
      (__attribute__((address_space(1))) void*)g,
      (__attribute__((address_space(3))) void*)l, 16, 0, 0);
}

// ---------------------------------------------------------------------------
// Router (proven)
// ---------------------------------------------------------------------------
__global__ __launch_bounds__(256) void router_kernel(
    const float* __restrict__ x, const float* __restrict__ gw,
    int* __restrict__ top_i, float* __restrict__ disp_w,
    float* __restrict__ p_sum, int* __restrict__ f_cnt) {
  __shared__ float s_p[NE];
  __shared__ int s_f[NE];
  if (threadIdx.x < NE) { s_p[threadIdx.x] = 0.0f; s_f[threadIdx.x] = 0; }
  __syncthreads();

  const int lane = threadIdx.x & 63;
  const int wv = threadIdx.x >> 6;
  const int n = blockIdx.x * 4 + wv;

  const float4* xr = (const float4*)(x + (size_t)n * ND);
  float acc[NE];
#pragma unroll
  for (int e = 0; e < NE; ++e) acc[e] = 0.0f;

#pragma unroll
  for (int q = 0; q < 4; ++q) {
    float4 xv = xr[lane * 4 + q];
#pragma unroll
    for (int e = 0; e < NE; ++e) {
      float4 g = ((const float4*)(gw + (size_t)e * ND))[lane * 4 + q];
      acc[e] += xv.x * g.x + xv.y * g.y + xv.z * g.z + xv.w * g.w;
    }
  }
#pragma unroll
  for (int m = 1; m < 64; m <<= 1) {
#pragma unroll
    for (int e = 0; e < NE; ++e) acc[e] += __shfl_xor(acc[e], m, 64);
  }

  float mx = acc[0];
#pragma unroll
  for (int e = 1; e < NE; ++e) mx = fmaxf(mx, acc[e]);
  float p[NE];
  float s = 0.0f;
#pragma unroll
  for (int e = 0; e < NE; ++e) { p[e] = expf(acc[e] - mx); s += p[e]; }
  float inv = 1.0f / s;
#pragma unroll
  for (int e = 0; e < NE; ++e) p[e] *= inv;

  int i1 = 0; float v1 = p[0];
#pragma unroll
  for (int e = 1; e < NE; ++e) { if (p[e] > v1) { v1 = p[e]; i1 = e; } }
  int i2 = 0; float v2 = -1.0f;
#pragma unroll
  for (int e = 0; e < NE; ++e) { if (e != i1 && p[e] > v2) { v2 = p[e]; i2 = e; } }

  if (lane == 0) {
    float dsum = v1 + v2 + 1e-9f;
    top_i[n * NK + 0] = i1;
    top_i[n * NK + 1] = i2;
    disp_w[n * NK + 0] = v1 / dsum;
    disp_w[n * NK + 1] = v2 / dsum;
#pragma unroll
    for (int e = 0; e < NE; ++e) atomicAdd(&s_p[e], p[e]);
    atomicAdd(&s_f[i1], 1);
    atomicAdd(&s_f[i2], 1);
  }
  __syncthreads();
  if (threadIdx.x < NE) {
    atomicAdd(&p_sum[threadIdx.x], s_p[threadIdx.x]);
    atomicAdd(&f_cnt[threadIdx.x], s_f[threadIdx.x]);
  }
}

// ---------------------------------------------------------------------------
// Capacity scan (proven)
// ---------------------------------------------------------------------------
__global__ __launch_bounds__(512) void scan_kernel(
    const int* __restrict__ top_i, const float* __restrict__ disp_w,
    int* __restrict__ routed_tok, float* __restrict__ routed_w,
    int* __restrict__ counts, const float* __restrict__ p_sum,
    const int* __restrict__ f_cnt, float* __restrict__ aux_out) {
  __shared__ __align__(16) int s_top[NN * NK];
  for (int i = threadIdx.x; i < (NN * NK) / 4; i += 512)
    ((int4*)s_top)[i] = ((const int4*)top_i)[i];
  __syncthreads();

  const int e = threadIdx.x >> 6;
  const int lane = threadIdx.x & 63;
  int cnt = 0;
  for (int c = 0; c < (NN * NK) / 64; ++c) {
    int a = c * 64 + lane;
    int n = a & (NN - 1);
    int k = a >> 13;
    bool m = (s_top[n * NK + k] == e);
    unsigned long long mask = __ballot(m);
    if (m) {
      int pos = cnt + __popcll(mask & ((1ull << lane) - 1ull));
      if (pos < NCAP) {
        routed_tok[e * NCAP + pos] = n;
        routed_w[e * NCAP + pos] = disp_w[n * NK + k];
      }
    }
    cnt += (int)__popcll(mask);
  }
  if (lane == 0) counts[e] = (cnt < NCAP) ? cnt : NCAP;

  if (threadIdx.x == 0) {
    float aux = 0.0f;
    for (int j = 0; j < NE; ++j)
      aux += (p_sum[j] / (float)NN) * ((float)f_cnt[j] / (float)NN);
    aux_out[0] = aux * (float)NE;
  }
}

// ---------------------------------------------------------------------------
// tsplit: W [E][K][N] f32 -> T [E][N][K] bf16 hi/lo, 64x64 tiles, 256 thr.
// Output: 4 consecutive threads cover 128B contiguous per row per buffer.
// LDS pad 65: k-group stride 16*65 % 32 = 16 -> 2-way (free) on reads.
// ---------------------------------------------------------------------------
__global__ __launch_bounds__(256) void tsplit_kernel(
    const float* __restrict__ W, ushort_t* __restrict__ Thi,
    ushort_t* __restrict__ Tlo, int K, int N) {
  __shared__ float tile[64][65];
  const int t = threadIdx.x;
  const int n0 = blockIdx.x * 64, k0 = blockIdx.y * 64;
  {
    const int r = t >> 2, c16 = (t & 3) * 16;
    const float* src = W + (size_t)blockIdx.z * K * N +
                       (size_t)(k0 + r) * N + n0 + c16;
#pragma unroll
    for (int q = 0; q < 4; ++q) {
      float4 v = *(const float4*)(src + q * 4);
      tile[r][c16 + q * 4 + 0] = v.x;
      tile[r][c16 + q * 4 + 1] = v.y;
      tile[r][c16 + q * 4 + 2] = v.z;
      tile[r][c16 + q * 4 + 3] = v.w;
    }
  }
  __syncthreads();
  const int n = t >> 2, kc = (t & 3) * 16;
  u16x8 h0, h1, l0, l1;
#pragma unroll
  for (int j = 0; j < 8; ++j) {
    float f = tile[kc + j][n];
    unsigned short h = f2bf(f);
    h0[j] = h; l0[j] = f2bf(f - bf2f(h));
  }
#pragma unroll
  for (int j = 0; j < 8; ++j) {
    float f = tile[kc + 8 + j][n];
    unsigned short h = f2bf(f);
    h1[j] = h; l1[j] = f2bf(f - bf2f(h));
  }
  size_t o = (size_t)blockIdx.z * N * K + (size_t)(n0 + n) * K + k0 + kc;
  *(u16x8*)(Thi + o) = h0;
  *(u16x8*)(Thi + o + 8) = h1;
  *(u16x8*)(Tlo + o) = l0;
  *(u16x8*)(Tlo + o + 8) = l1;
}

// ---------------------------------------------------------------------------
// fgemm_fused: split-bf16 MFMA GEMM, 128x128 tile, 4 waves (2x2 of 64x64),
// 256 threads, BK=32, KLOOP=1024. 32 KB LDS -> 3 blocks/CU (regs ~136/wave
// = 3 waves/SIMD), so barrier drains overlap across co-resident blocks.
// Role by blockIdx.z: z < n_g1_z -> G1 (expert z): H[chunk]=gelu(x@W1+b1),
//   A reg-staged from f32 x (split in-register, ds_write to swizzled slots).
// else -> G2: out += w*(H[chunk]@W2+b2); split-K2 via bx>>3 (bias on kseg 0),
//   A via global_load_lds from split H. Same swizzle involution both sides.
// ---------------------------------------------------------------------------
__global__ __launch_bounds__(256, 3) void fgemm_fused(
    const float* __restrict__ x,
    const ushort_t* __restrict__ w1hi, const ushort_t* __restrict__ w1lo,
    const float* __restrict__ b1,
    const ushort_t* __restrict__ w2hi, const ushort_t* __restrict__ w2lo,
    const float* __restrict__ b2,
    const ushort_t* __restrict__ Hrhi, const ushort_t* __restrict__ Hrlo,
    ushort_t* __restrict__ Hwhi, ushort_t* __restrict__ Hwlo,
    const int* __restrict__ routed_tok, const float* __restrict__ routed_w,
    const int* __restrict__ counts, float* __restrict__ outf,
    int n_g1_z, int g1_lo, int g2_lo, int Rh) {
  const int bz = blockIdx.z;
  const bool isG1 = bz < n_g1_z;
  const int e = isG1 ? bz : bz - n_g1_z;
  const int count = counts[e];
  const int chunk_lo = isG1 ? g1_lo : g2_lo;
  const int local0 = blockIdx.y * 128;
  const int row0 = chunk_lo + local0;
  if (row0 >= count) return;
  const int bx = blockIdx.x;
  const int col0 = isG1 ? bx * 128 : (bx & 7) * 128;
  const int koff = isG1 ? 0 : (bx >> 3) * 1024;
  const int Ntot = isG1 ? NDFF : ND;
  const int Bstride = isG1 ? ND : NDFF;   // K-length of B rows

  __shared__ __align__(16) char lds[32768];
  char* ldsA = lds;             // 16 KB: 128 rows x 8 chunks x 16B
  char* ldsB = lds + 16384;     // 16 KB: 128 cols x 8 chunks x 16B

  const int t = threadIdx.x;
  const int lane = t & 63;
  const int wid = t >> 6;            // 0..3
  const int wr = wid >> 1, wc = wid & 1;
  const int fr = lane & 15, ko = lane >> 4;

  // ---- A staging setup ----
  const float* srcAf = nullptr;      // G1: f32 x row segment
  char* dstA[4] = {nullptr, nullptr, nullptr, nullptr};
  const ushort_t* srcA[4];           // G2: split-H gload_lds sources
  if (isG1) {
    const int r = t >> 1, kp = (t & 1) * 2;   // row 0..127, k-chunk pair
    const int rr = row0 + r;
    const int tok = routed_tok[e * NCAP + (rr < count ? rr : 0)];
    srcAf = x + (size_t)tok * ND + kp * 8;
    const int s = r & 7;
    dstA[0] = ldsA + (size_t)(r * 8 + ((kp + 0) ^ s)) * 16;  // hi chunk kp
    dstA[1] = ldsA + (size_t)(r * 8 + ((kp + 1) ^ s)) * 16;  // hi chunk kp+1
    dstA[2] = ldsA + (size_t)(r * 8 + ((kp + 4) ^ s)) * 16;  // lo chunk kp+4
    dstA[3] = ldsA + (size_t)(r * 8 + ((kp + 5) ^ s)) * 16;  // lo chunk kp+5
  } else {
#pragma unroll
    for (int c = 0; c < 4; ++c) {
      int ci = t + 256 * c;               // 0..1023
      int r = ci >> 3, bp = ci & 7;
      int bs = bp ^ (r & 7);
      size_t arow = (size_t)e * Rh + local0 + r;
      srcA[c] = (bs < 4 ? Hrhi : Hrlo) + arow * (size_t)NDFF + koff + (bs & 3) * 8;
    }
  }
  // ---- B staging setup ----
  const ushort_t* Bh = isG1 ? w1hi : w2hi;
  const ushort_t* Bl = isG1 ? w1lo : w2lo;
  const ushort_t* srcB[4];
#pragma unroll
  for (int c = 0; c < 4; ++c) {
    int ci = t + 256 * c;                 // 0..1023
    int cc = ci >> 3, bp = ci & 7;
    int bs = bp ^ (cc & 7);
    srcB[c] = (bs < 4 ? Bh : Bl) +
              ((size_t)e * Ntot + col0 + cc) * (size_t)Bstride + koff + (bs & 3) * 8;
  }

  f32x4 acc[4][4] = {};

  for (int ks = 0; ks < 1024; ks += 32) {
    if (isG1) {
      float4 v0 = *(const float4*)(srcAf);
      float4 v1 = *(const float4*)(srcAf + 4);
      float4 v2 = *(const float4*)(srcAf + 8);
      float4 v3 = *(const float4*)(srcAf + 12);
      srcAf += 32;
      u16x8 h0, h1, l0, l1;
      unsigned short h; float f;
      f = v0.x; h = f2bf(f); h0[0] = h; l0[0] = f2bf(f - bf2f(h));
      f = v0.y; h = f2bf(f); h0[1] = h; l0[1] = f2bf(f - bf2f(h));
      f = v0.z; h = f2bf(f); h0[2] = h; l0[2] = f2bf(f - bf2f(h));
      f = v0.w; h = f2bf(f); h0[3] = h; l0[3] = f2bf(f - bf2f(h));
      f = v1.x; h = f2bf(f); h0[4] = h; l0[4] = f2bf(f - bf2f(h));
      f = v1.y; h = f2bf(f); h0[5] = h; l0[5] = f2bf(f - bf2f(h));
      f = v1.z; h = f2bf(f); h0[6] = h; l0[6] = f2bf(f - bf2f(h));
      f = v1.w; h = f2bf(f); h0[7] = h; l0[7] = f2bf(f - bf2f(h));
      f = v2.x; h = f2bf(f); h1[0] = h; l1[0] = f2bf(f - bf2f(h));
      f = v2.y; h = f2bf(f); h1[1] = h; l1[1] = f2bf(f - bf2f(h));
      f = v2.z; h = f2bf(f); h1[2] = h; l1[2] = f2bf(f - bf2f(h));
      f = v2.w; h = f2bf(f); h1[3] = h; l1[3] = f2bf(f - bf2f(h));
      f = v3.x; h = f2bf(f); h1[4] = h; l1[4] = f2bf(f - bf2f(h));
      f = v3.y; h = f2bf(f); h1[5] = h; l1[5] = f2bf(f - bf2f(h));
      f = v3.z; h = f2bf(f); h1[6] = h; l1[6] = f2bf(f - bf2f(h));
      f = v3.w; h = f2bf(f); h1[7] = h; l1[7] = f2bf(f - bf2f(h));
      *(u16x8*)dstA[0] = h0;
      *(u16x8*)dstA[1] = h1;
      *(u16x8*)dstA[2] = l0;
      *(u16x8*)dstA[3] = l1;
    } else {
#pragma unroll
      for (int c = 0; c < 4; ++c) {
        gl_lds16(srcA[c], ldsA + (c * 256 + wid * 64) * 16);
        srcA[c] += 32;
      }
    }
#pragma unroll
    for (int c = 0; c < 4; ++c) {
      gl_lds16(srcB[c], ldsB + (c * 256 + wid * 64) * 16);
      srcB[c] += 32;
    }
    __syncthreads();

    bf16x8 Ah[4], Al[4], Bhf[4], Blf[4];
#pragma unroll
    for (int fi = 0; fi < 4; ++fi) {
      int r = wr * 64 + fi * 16 + fr;
      Ah[fi] = *(const bf16x8*)(ldsA + r * 128 + ((ko ^ (r & 7)) << 4));
      Al[fi] = *(const bf16x8*)(ldsA + r * 128 + (((4 + ko) ^ (r & 7)) << 4));
    }
#pragma unroll
    for (int fj = 0; fj < 4; ++fj) {
      int cc = wc * 64 + fj * 16 + fr;
      Bhf[fj] = *(const bf16x8*)(ldsB + cc * 128 + ((ko ^ (cc & 7)) << 4));
      Blf[fj] = *(const bf16x8*)(ldsB + cc * 128 + (((4 + ko) ^ (cc & 7)) << 4));
    }
#pragma unroll
    for (int fi = 0; fi < 4; ++fi)
#pragma unroll
      for (int fj = 0; fj < 4; ++fj) {
        acc[fi][fj] = __builtin_amdgcn_mfma_f32_16x16x32_bf16(
            Ah[fi], Bhf[fj], acc[fi][fj], 0, 0, 0);
        acc[fi][fj] = __builtin_amdgcn_mfma_f32_16x16x32_bf16(
            Ah[fi], Blf[fj], acc[fi][fj], 0, 0, 0);
        acc[fi][fj] = __builtin_amdgcn_mfma_f32_16x16x32_bf16(
            Al[fi], Bhf[fj], acc[fi][fj], 0, 0, 0);
      }
    __syncthreads();
  }

  // C/D layout (verified): col = lane&15, row = (lane>>4)*4 + reg
  const float* bias = isG1 ? b1 : b2;
  float bv[4];
#pragma unroll
  for (int fj = 0; fj < 4; ++fj)
    bv[fj] = (koff == 0)
                 ? bias[(size_t)e * Ntot + col0 + wc * 64 + fj * 16 + fr]
                 : 0.0f;

  if (isG1) {
#pragma unroll
    for (int fi = 0; fi < 4; ++fi) {
#pragma unroll
      for (int rg = 0; rg < 4; ++rg) {
        int rr = row0 + wr * 64 + fi * 16 + ko * 4 + rg;
        if (rr < count) {
          size_t rb = ((size_t)e * Rh + (rr - chunk_lo)) * (size_t)NDFF;
#pragma unroll
          for (int fj = 0; fj < 4; ++fj) {
            int cc = col0 + wc * 64 + fj * 16 + fr;
            float g = gelu_exact(acc[fi][fj][rg] + bv[fj]);
            unsigned short hh = f2bf(g);
            Hwhi[rb + cc] = hh;
            Hwlo[rb + cc] = f2bf(g - bf2f(hh));
          }
        }
      }
    }
  } else {
#pragma unroll
    for (int fi = 0; fi < 4; ++fi) {
#pragma unroll
      for (int rg = 0; rg < 4; ++rg) {
        int rr = row0 + wr * 64 + fi * 16 + ko * 4 + rg;
        if (rr < count) {
          int tok = routed_tok[e * NCAP + rr];
          float wgt = routed_w[e * NCAP + rr];
          float* orow = outf + (size_t)tok * ND;
#pragma unroll
          for (int fj = 0; fj < 4; ++fj) {
            int cc = col0 + wc * 64 + fj * 16 + fr;
            atomicAdd(orow + cc, wgt * (acc[fi][fj][rg] + bv[fj]));
          }
        }
      }
    }
  }
}

// ---------------------------------------------------------------------------
// fp32 vector fallback (proven round 4) — only if ws can't fit the fast path
// ---------------------------------------------------------------------------
__global__ __launch_bounds__(256) void gemm1_kernel(
    const float* __restrict__ x, const float* __restrict__ W1,
    const float* __restrict__ b1, const int* __restrict__ routed_tok,
    const int* __restrict__ counts, float* __restrict__ H,
    int e0, size_t h_stride) {
  const int e = e0 + blockIdx.z;
  const int count = counts[e];
  const int row0 = blockIdx.y * 128;
  if (row0 >= count) return;
  const int col0 = blockIdx.x * 128;
  const float* W = W1 + (size_t)e * ND * NDFF;
  float* Hb = H + (size_t)blockIdx.z * h_stride;

  __shared__ __align__(16) float As[16][128];
  __shared__ __align__(16) float Bs[16][128];

  const int tid = threadIdx.x;
  const int arow = tid >> 1;
  const int aq = (tid & 1) * 8;
  const int r = row0 + arow;
  const int tok = routed_tok[e * NCAP + (r < count ? r : 0)];
  const float* Arow = x + (size_t)tok * ND;
  const int bk = tid >> 5;
  const int bc = (tid & 31) * 4;
  const int ty = tid >> 4, tx = tid & 15;

  float c[8][8] = {};

  for (int k0 = 0; k0 < ND; k0 += 16) {
    float4 av0 = *(const float4*)(Arow + k0 + aq);
    float4 av1 = *(const float4*)(Arow + k0 + aq + 4);
    float4 bv0 = *(const float4*)(W + (size_t)(k0 + bk) * NDFF + col0 + bc);
    float4 bv1 = *(const float4*)(W + (size_t)(k0 + bk + 8) * NDFF + col0 + bc);
    __syncthreads();
    As[aq + 0][arow] = av0.x; As[aq + 1][arow] = av0.y;
    As[aq + 2][arow] = av0.z; As[aq + 3][arow] = av0.w;
    As[aq + 4][arow] = av1.x; As[aq + 5][arow] = av1.y;
    As[aq + 6][arow] = av1.z; As[aq + 7][arow] = av1.w;
    *(float4*)&Bs[bk][bc] = bv0;
    *(float4*)&Bs[bk + 8][bc] = bv1;
    __syncthreads();
#pragma unroll
    for (int kk = 0; kk < 16; ++kk) {
      float4 a0 = *(const float4*)&As[kk][ty * 4];
      float4 a1 = *(const float4*)&As[kk][ty * 4 + 64];
      float4 b0 = *(const float4*)&Bs[kk][tx * 4];
      float4 b1r = *(const float4*)&Bs[kk][tx * 4 + 64];
      float ar[8] = {a0.x, a0.y, a0.z, a0.w, a1.x, a1.y, a1.z, a1.w};
      float br[8] = {b0.x, b0.y, b0.z, b0.w, b1r.x, b1r.y, b1r.z, b1r.w};
#pragma unroll
      for (int i = 0; i < 8; ++i)
#pragma unroll
        for (int j = 0; j < 8; ++j)
          c[i][j] = fmaf(ar[i], br[j], c[i][j]);
    }
  }

  const float* b1e = b1 + (size_t)e * NDFF + col0;
#pragma unroll
  for (int i = 0; i < 8; ++i) {
    int rr = row0 + ty * 4 + (i & 3) + (i >> 2) * 64;
    if (rr < count) {
      float* Hr = Hb + (size_t)rr * NDFF + col0;
      float4 v0, v1;
      v0.x = gelu_exact(c[i][0] + b1e[tx * 4 + 0]);
      v0.y = gelu_exact(c[i][1] + b1e[tx * 4 + 1]);
      v0.z = gelu_exact(c[i][2] + b1e[tx * 4 + 2]);
      v0.w = gelu_exact(c[i][3] + b1e[tx * 4 + 3]);
      v1.x = gelu_exact(c[i][4] + b1e[tx * 4 + 64]);
      v1.y = gelu_exact(c[i][5] + b1e[tx * 4 + 65]);
      v1.z = gelu_exact(c[i][6] + b1e[tx * 4 + 66]);
      v1.w = gelu_exact(c[i][7] + b1e[tx * 4 + 67]);
      *(float4*)(Hr + tx * 4) = v0;
      *(float4*)(Hr + tx * 4 + 64) = v1;
    }
  }
}

__global__ __launch_bounds__(256) void gemm2_kernel(
    const float* __restrict__ H, const float* __restrict__ W2,
    const float* __restrict__ b2, const int* __restrict__ routed_tok,
    const float* __restrict__ routed_w, const int* __restrict__ counts,
    float* __restrict__ out, int e0, size_t h_stride) {
  const int e = e0 + blockIdx.z;
  const int count = counts[e];
  const int row0 = blockIdx.y * 128;
  if (row0 >= count) return;
  const int col0 = blockIdx.x * 128;
  const float* W = W2 + (size_t)e * NDFF * ND;
  const float* Hb = H + (size_t)blockIdx.z * h_stride;

  __shared__ __align__(16) float As[16][128];
  __shared__ __align__(16) float Bs[16][128];

  const int tid = threadIdx.x;
  const int arow = tid >> 1;
  const int aq = (tid & 1) * 8;
  const float* Arow = Hb + (size_t)(row0 + arow) * NDFF;
  const int bk = tid >> 5;
  const int bc = (tid & 31) * 4;
  const int ty = tid >> 4, tx = tid & 15;

  float c[8][8] = {};

  for (int k0 = 0; k0 < NDFF; k0 += 16) {
    float4 av0 = *(const float4*)(Arow + k0 + aq);
    float4 av1 = *(const float4*)(Arow + k0 + aq + 4);
    float4 bv0 = *(const float4*)(W + (size_t)(k0 + bk) * ND + col0 + bc);
    float4 bv1 = *(const float4*)(W + (size_t)(k0 + bk + 8) * ND + col0 + bc);
    __syncthreads();
    As[aq + 0][arow] = av0.x; As[aq + 1][arow] = av0.y;
    As[aq + 2][arow] = av0.z; As[aq + 3][arow] = av0.w;
    As[aq + 4][arow] = av1.x; As[aq + 5][arow] = av1.y;
    As[aq + 6][arow] = av1.z; As[aq + 7][arow] = av1.w;
    *(float4*)&Bs[bk][bc] = bv0;
    *(float4*)&Bs[bk + 8][bc] = bv1;
    __syncthreads();
#pragma unroll
    for (int kk = 0; kk < 16; ++kk) {
      float4 a0 = *(const float4*)&As[kk][ty * 4];
      float4 a1 = *(const float4*)&As[kk][ty * 4 + 64];
      float4 b0 = *(const float4*)&Bs[kk][tx * 4];
      float4 b1r = *(const float4*)&Bs[kk][tx * 4 + 64];
      float ar[8] = {a0.x, a0.y, a0.z, a0.w, a1.x, a1.y, a1.z, a1.w};
      float br[8] = {b0.x, b0.y, b0.z, b0.w, b1r.x, b1r.y, b1r.z, b1r.w};
#pragma unroll
      for (int i = 0; i < 8; ++i)
#pragma unroll
        for (int j = 0; j < 8; ++j)
          c[i][j] = fmaf(ar[i], br[j], c[i][j]);
    }
  }

  const float* b2e = b2 + (size_t)e * ND + col0;
#pragma unroll
  for (int i = 0; i < 8; ++i) {
    int rr = row0 + ty * 4 + (i & 3) + (i >> 2) * 64;
    if (rr < count) {
      int tok = routed_tok[e * NCAP + rr];
      float wgt = routed_w[e * NCAP + rr];
      float* orow = out + (size_t)tok * ND + col0;
#pragma unroll
      for (int j = 0; j < 8; ++j) {
        int cc = tx * 4 + (j & 3) + (j >> 2) * 64;
        atomicAdd(orow + cc, wgt * (c[i][j] + b2e[cc]));
      }
    }
  }
}

// ---------------------------------------------------------------------------
extern "C" void kernel_launch(void* const* d_in, const int* in_sizes, int n_in,
                              void* d_out, int out_size, void* d_ws, size_t ws_size,
                              hipStream_t stream) {
  const float* x  = (const float*)d_in[0];
  const float* gw = (const float*)d_in[1];
  const float* W1 = (const float*)d_in[2];
  const float* b1 = (const float*)d_in[3];
  const float* W2 = (const float*)d_in[4];
  const float* b2 = (const float*)d_in[5];
  float* out = (float*)d_out;

  char* p = (char*)d_ws;
  auto alloc = [&](size_t bytes) -> char* {
    char* q = p;
    p += (bytes + 255) & ~(size_t)255;
    return q;
  };

  int*   top_i = (int*)alloc((size_t)NN * NK * 4);
  float* dispw = (float*)alloc((size_t)NN * NK * 4);
  int*   rtok  = (int*)alloc((size_t)NE * NCAP * 4);
  float* rw    = (float*)alloc((size_t)NE * NCAP * 4);
  int*   counts = (int*)alloc(256);
  float* psum  = (float*)alloc(64);
  int*   fcnt  = (int*)((char*)psum + 32);
  char*  p_base = p;

  hipMemsetAsync(out, 0, (size_t)NN * ND * 4, stream);
  hipMemsetAsync(psum, 0, 64, stream);

  router_kernel<<<NN / 4, 256, 0, stream>>>(x, gw, top_i, dispw, psum, fcnt);
  scan_kernel<<<1, 512, 0, stream>>>(top_i, dispw, rtok, rw, counts, psum, fcnt,
                                     out + (size_t)NN * ND);

  // ---- plan the GEMM path from ws_size ----
  const size_t sw = (size_t)NE * ND * NDFF * 2;          // 32 MiB per split array
  const size_t perRow = (size_t)NE * NDFF * 2 * 2;       // 64 KiB per H row slot
  size_t wt_end = (size_t)(p_base - (char*)d_ws) + 4 * (sw + 256);
  size_t avail = (ws_size > wt_end + 8192) ? ws_size - wt_end - 8192 : 0;

  int Rh = 0;
  bool full = false;
  if (avail >= (size_t)NCAP * perRow) {
    full = true; Rh = NCAP;
  } else {
    Rh = (int)((avail / (2 * perRow)) & ~(size_t)127);
    if (Rh > NCAP - 128) Rh = NCAP - 128;
  }

  if (Rh >= 128) {
    // ---------------- split-bf16 MFMA path ----------------
    ushort_t* w1hi = (ushort_t*)alloc(sw);
    ushort_t* w1lo = (ushort_t*)alloc(sw);
    ushort_t* w2hi = (ushort_t*)alloc(sw);
    ushort_t* w2lo = (ushort_t*)alloc(sw);

    tsplit_kernel<<<dim3(NDFF / 64, ND / 64, NE), 256, 0, stream>>>(
        W1, w1hi, w1lo, ND, NDFF);
    tsplit_kernel<<<dim3(ND / 64, NDFF / 64, NE), 256, 0, stream>>>(
        W2, w2hi, w2lo, NDFF, ND);

    const size_t hb = (size_t)NE * Rh * NDFF * 2;
    if (full) {
      ushort_t* Hhi = (ushort_t*)alloc(hb);
      ushort_t* Hlo = (ushort_t*)alloc(hb);
      fgemm_fused<<<dim3(16, NCAP / 128, 8), 256, 0, stream>>>(
          x, w1hi, w1lo, b1, w2hi, w2lo, b2, Hhi, Hlo, Hhi, Hlo,
          rtok, rw, counts, out, 8, 0, 0, Rh);
      fgemm_fused<<<dim3(16, NCAP / 128, 8), 256, 0, stream>>>(
          x, w1hi, w1lo, b1, w2hi, w2lo, b2, Hhi, Hlo, Hhi, Hlo,
          rtok, rw, counts, out, 0, 0, 0, Rh);
    } else {
      ushort_t* h0hi = (ushort_t*)alloc(hb);
      ushort_t* h0lo = (ushort_t*)alloc(hb);
      ushort_t* h1hi = (ushort_t*)alloc(hb);
      ushort_t* h1lo = (ushort_t*)alloc(hb);
      ushort_t* bh[2] = {h0hi, h1hi};
      ushort_t* bl[2] = {h0lo, h1lo};
      const int P = (NCAP + Rh - 1) / Rh;
      const int ylen = Rh / 128;
      // L0: g1(chunk 0)
      fgemm_fused<<<dim3(16, ylen, 8), 256, 0, stream>>>(
          x, w1hi, w1lo, b1, w2hi, w2lo, b2, bh[0], bl[0], bh[0], bl[0],
          rtok, rw, counts, out, 8, 0, 0, Rh);
      // Li: g2(chunk i-1) merged with g1(chunk i)
      for (int i = 1; i < P; ++i) {
        fgemm_fused<<<dim3(16, ylen, 16), 256, 0, stream>>>(
            x, w1hi, w1lo, b1, w2hi, w2lo, b2,
            bh[(i - 1) & 1], bl[(i - 1) & 1], bh[i & 1], bl[i & 1],
            rtok, rw, counts, out, 8, i * Rh, (i - 1) * Rh, Rh);
      }
      // LP: g2(last chunk)
      fgemm_fused<<<dim3(16, ylen, 8), 256, 0, stream>>>(
          x, w1hi, w1lo, b1, w2hi, w2lo, b2,
          bh[(P - 1) & 1], bl[(P - 1) & 1], bh[(P - 1) & 1], bl[(P - 1) & 1],
          rtok, rw, counts, out, 0, 0, (P - 1) * Rh, Rh);
    }
  } else {
    // ---------------- fp32 vector fallback (proven) ----------------
    p = p_base;
    float* H = (float*)p;
    const size_t need_old_full =
        (size_t)(p_base - (char*)d_ws) + (size_t)NE * NCAP * NDFF * 4 + 8192;
    const bool fullH = (ws_size >= need_old_full);
    if (fullH) {
      gemm1_kernel<<<dim3(NDFF / 128, NCAP / 128, NE), 256, 0, stream>>>(
          x, W1, b1, rtok, counts, H, 0, (size_t)NCAP * NDFF);
      gemm2_kernel<<<dim3(ND / 128, NCAP / 128, NE), 256, 0, stream>>>(
          H, W2, b2, rtok, rw, counts, out, 0, (size_t)NCAP * NDFF);
    } else {
      for (int e = 0; e < NE; ++e) {
        gemm1_kernel<<<dim3(NDFF / 128, NCAP / 128, 1), 256, 0, stream>>>(
            x, W1, b1, rtok, counts, H, e, 0);
        gemm2_kernel<<<dim3(ND / 128, NCAP / 128, 1), 256, 0, stream>>>(
            H, W2, b2, rtok, rw, counts, out, e, 0);
      }
    }
  }
}